// Round 1
// 130.299 us; speedup vs baseline: 1.0102x; 1.0102x over previous
//
#include <hip/hip_runtime.h>

#define NM 23        // 3*K - 1, K = 8

typedef short short8 __attribute__((ext_vector_type(8)));
typedef float f32x4 __attribute__((ext_vector_type(4)));

__device__ __forceinline__ float softplus_f(float v) {
  return fmaxf(v, 0.f) + __logf(1.f + __expf(-fabsf(v)));
}

__device__ __forceinline__ unsigned short bf16_rne(float x) {
  unsigned u = __float_as_uint(x);
  u += 0x7FFFu + ((u >> 16) & 1u);
  return (unsigned short)(u >> 16);
}

// ---------------------------------------------------------------------------
// Prep (R11-validated): pre-masked L1/L2 weights + W3 as MFMA B-fragments
// (bf16 hi/lo split). B[k][n]: n=lane&15, k=(lane>>4)*8+j; n = m*64+d.
// Stored lane-contiguous 16B. Coverage: 184*256 = 47104 exact.
// ---------------------------------------------------------------------------
__global__ __launch_bounds__(256) void prep_kernel(
    const float* __restrict__ W1, const float* __restrict__ W2,
    const float* __restrict__ W3,
    float* __restrict__ W1t, float* __restrict__ W2t,
    unsigned short* __restrict__ Bhi, unsigned short* __restrict__ Blo) {
  const int idx = blockIdx.x * 256 + threadIdx.x;
  if (idx < 64 * 64) {                  // W1t[d][i] = mask * W1[i][d]
    const int d = idx >> 6, i = idx & 63;
    W1t[idx] = ((i % 63) >= d) ? W1[i * 64 + d] : 0.f;
  }
  if (idx < 64 * 32) {                  // W2t[i][j] = mask * W2[j][i]
    const int i = idx >> 5, j = idx & 31;
    W2t[idx] = ((i % 63) <= j) ? W2[j * 64 + i] : 0.f;
  }
  if (idx < 92 * 64 * 8) {              // B fragments
    const int nt = idx >> 9;
    const int rem = idx & 511;
    const int lane = rem >> 3, j = rem & 7;
    const int col = lane & 15, quad = lane >> 4;
    const int n = nt * 16 + col;        // n = m*64 + d
    const int d = n & 63;
    const int k = quad * 8 + j;
    const float v = (k < d) ? W3[(size_t)n * 32 + k] : 0.f;
    const unsigned short h = bf16_rne(v);
    const float hf = __uint_as_float(((unsigned)h) << 16);
    Bhi[idx] = h;
    Blo[idx] = bf16_rne(v - hf);
  }
}

// ---------------------------------------------------------------------------
// Fused kernel. R15 CHANGE: merge the two d-half blocks into ONE block per
// 64-row tile (grid 1024 -> 512). Layers 1/2 (the per-thread fmac phases,
// ~1536 FMA/thread) depended only on the row-block, not the d-half — they
// were computed TWICE globally. The jj d-chunk loop (unroll 1, accumulators
// live only inside) extends 2 -> 4 chunks at zero extra register cost.
// Bonus: the 4 chunks cover all 64 d in-block, so the log-det shfl-reduce
// is now complete — ldws buffer and the ld_reduce dispatch are eliminated.
// Numerics for z are instruction-identical to the validated R14 kernel.
// ---------------------------------------------------------------------------
__global__ __launch_bounds__(256, 2) void fused_kernel(
    const float* __restrict__ x,
    const float* __restrict__ W1t, const float* __restrict__ b1,
    const float* __restrict__ W2t, const float* __restrict__ b2,
    const unsigned short* __restrict__ Bhi,
    const unsigned short* __restrict__ Blo,
    const float* __restrict__ b3,
    float* __restrict__ out, int B) {
  __shared__ float xs[64][68];     // x in; z in-place
  __shared__ float h1s[64][65];
  __shared__ float h2s[64][36];    // stride 36: 16B-aligned b128 A-frag reads
  __shared__ float b3s[64 * NM];   // all 64 d biases: [d][m]

  const int t = threadIdx.x;
  const int rb = blockIdx.x;            // row-block
  const int b0 = rb * 64;

  // ---- stage x: 64x64, 4 float4/thread, coalesced ----
  #pragma unroll
  for (int u = 0; u < 4; ++u) {
    const int idx = t + u * 256;
    const int rr = idx >> 4, c4 = (idx & 15) * 4;
    const float4 v = *reinterpret_cast<const float4*>(
        x + (size_t)b0 * 64 + (size_t)idx * 4);
    xs[rr][c4 + 0] = v.x; xs[rr][c4 + 1] = v.y;
    xs[rr][c4 + 2] = v.z; xs[rr][c4 + 3] = v.w;
  }
  // ---- stage b3 for all d: b3s[d*NM+m] = b3[m*64 + d] ----
  for (int idx = t; idx < 64 * NM; idx += 256) {
    const int dl = idx / NM, m = idx - dl * NM;
    b3s[idx] = b3[m * 64 + dl];
  }
  __syncthreads();

  const int r  = t & 63;                                  // lane = row
  const int wv = __builtin_amdgcn_readfirstlane(t >> 6);  // wave 0..3

  // ---- layer 1: i in [wv*16, wv*16+16), pure fmac ----
  {
    const int iBase = wv * 16;
    float acc1[16];
    #pragma unroll
    for (int ii = 0; ii < 16; ++ii) acc1[ii] = b1[iBase + ii];
    #pragma unroll 4
    for (int dd = 0; dd < 64; ++dd) {
      const float xv = xs[r][dd];
      const float* wrow = W1t + dd * 64 + iBase;          // uniform s_load
      #pragma unroll
      for (int ii = 0; ii < 16; ++ii) acc1[ii] = fmaf(xv, wrow[ii], acc1[ii]);
    }
    #pragma unroll
    for (int ii = 0; ii < 16; ++ii) h1s[r][iBase + ii] = fmaxf(acc1[ii], 0.f);
  }
  __syncthreads();

  // ---- layer 2: j in [wv*8, wv*8+8), pure fmac ----
  {
    const int jBase = wv * 8;
    float acc2[8];
    #pragma unroll
    for (int jj = 0; jj < 8; ++jj) acc2[jj] = b2[jBase + jj];
    #pragma unroll 4
    for (int i2 = 0; i2 < 64; ++i2) {
      const float hv = h1s[r][i2];
      const float* wrow = W2t + i2 * 32 + jBase;          // uniform s_load
      #pragma unroll
      for (int jj = 0; jj < 8; ++jj) acc2[jj] = fmaf(hv, wrow[jj], acc2[jj]);
    }
    #pragma unroll
    for (int jj = 0; jj < 8; ++jj)
      h2s[r][jBase + jj] = fmaxf(acc2[jj], 0.f);
  }
  __syncthreads();

  // ---- MFMA layer 3 + spline ----
  const int lane = t & 63;
  const int mt   = wv;                  // M-tile: rows mt*16..mt*16+15
  const int col  = lane & 15;
  const int quad = lane >> 4;

  // A fragment: A[m=lane&15][k=quad*8+j] from h2, bf16 hi/lo split
  short8 ahi, alo;
  {
    const int arow = mt * 16 + col;
    const f32x4 a0 = *reinterpret_cast<const f32x4*>(&h2s[arow][quad * 8]);
    const f32x4 a1 = *reinterpret_cast<const f32x4*>(&h2s[arow][quad * 8 + 4]);
    float af[8] = {a0.x, a0.y, a0.z, a0.w, a1.x, a1.y, a1.z, a1.w};
    #pragma unroll
    for (int j = 0; j < 8; ++j) {
      const unsigned short h = bf16_rne(af[j]);
      ahi[j] = (short)h;
      alo[j] = (short)bf16_rne(af[j] - __uint_as_float(((unsigned)h) << 16));
    }
  }

  float ldr[4] = {0.f, 0.f, 0.f, 0.f};

  #pragma unroll 1
  for (int jj = 0; jj < 4; ++jj) {
    const int dc = jj;                                    // d-chunk 0..3
    const int d  = dc * 16 + col;                         // this lane's d

    // bias pre-folded into accumulator init (C = A*B + bias)
    f32x4 acc[NM];
    #pragma unroll
    for (int m = 0; m < NM; ++m) {
      const float bv = b3s[d * NM + m];
      acc[m] = (f32x4){bv, bv, bv, bv};
    }
    #pragma unroll
    for (int m = 0; m < NM; ++m) {
      const int nt = 4 * m + dc;
      const size_t off = ((size_t)nt * 64 + lane) * 8;
      const short8 bh = *reinterpret_cast<const short8*>(Bhi + off);
      const short8 bl = *reinterpret_cast<const short8*>(Blo + off);
      acc[m] = __builtin_amdgcn_mfma_f32_16x16x32_bf16(ahi, bh, acc[m], 0, 0, 0);
      acc[m] = __builtin_amdgcn_mfma_f32_16x16x32_bf16(alo, bh, acc[m], 0, 0, 0);
      acc[m] = __builtin_amdgcn_mfma_f32_16x16x32_bf16(ahi, bl, acc[m], 0, 0, 0);
    }

    // spline: 4 rows per lane (C rows quad*4+reg), this lane's d
    #pragma unroll
    for (int reg = 0; reg < 4; ++reg) {
      const int row = mt * 16 + quad * 4 + reg;

      float p[NM];
      #pragma unroll
      for (int m = 0; m < NM; ++m) p[m] = acc[m][reg];

      const float xv = xs[row][d];
      const float xc = fminf(fmaxf(xv, -3.f), 3.f);

      float mw = p[0];
      #pragma unroll
      for (int k = 1; k < 8; ++k) mw = fmaxf(mw, p[k]);
      float ew[8], sw = 0.f;
      #pragma unroll
      for (int k = 0; k < 8; ++k) { ew[k] = __expf(p[k] - mw); sw += ew[k]; }
      const float invw = 1.f / sw;

      float mh = p[8];
      #pragma unroll
      for (int k = 1; k < 8; ++k) mh = fmaxf(mh, p[8 + k]);
      float eh[8], sh = 0.f;
      #pragma unroll
      for (int k = 0; k < 8; ++k) { eh[k] = __expf(p[8 + k] - mh); sh += eh[k]; }
      const float invh = 1.f / sh;

      const float WSC = 1.0f - 1e-3f * 8.0f;
      float cumw[9], cumh[9];
      cumw[0] = -3.f; cumh[0] = -3.f;
      float cw = 0.f, ch = 0.f;
      #pragma unroll
      for (int k = 0; k < 7; ++k) {
        cw += 1e-3f + WSC * (ew[k] * invw);
        ch += 1e-3f + WSC * (eh[k] * invh);
        cumw[k + 1] = fmaf(6.f, cw, -3.f);
        cumh[k + 1] = fmaf(6.f, ch, -3.f);
      }
      cumw[8] = 3.f; cumh[8] = 3.f;

      float derivs[9];
      derivs[0] = 1.f; derivs[8] = 1.f;
      #pragma unroll
      for (int k = 0; k < 7; ++k) derivs[k + 1] = 1e-3f + softplus_f(p[16 + k]);

      float xk = cumw[0], xk1 = cumw[1];
      float yk = cumh[0], yk1 = cumh[1];
      float dk = derivs[0], dk1 = derivs[1];
      #pragma unroll
      for (int k = 1; k < 8; ++k) {
        const bool s = xc >= cumw[k] + 1e-6f;
        xk  = s ? cumw[k]       : xk;
        xk1 = s ? cumw[k + 1]   : xk1;
        yk  = s ? cumh[k]       : yk;
        yk1 = s ? cumh[k + 1]   : yk1;
        dk  = s ? derivs[k]     : dk;
        dk1 = s ? derivs[k + 1] : dk1;
      }

      const float wk = xk1 - xk, hk = yk1 - yk;
      const float invwk = 1.f / wk;
      const float delta = hk * invwk;
      const float theta = (xc - xk) * invwk;
      const float omt = 1.f - theta;
      const float tt = theta * omt;
      const float th2 = theta * theta;
      const float num = hk * (delta * th2 + dk * tt);
      const float den = delta + (dk + dk1 - 2.f * delta) * tt;
      const float yv = yk + num / den;
      const float dnum = delta * delta * (dk1 * th2 + 2.f * delta * tt + dk * omt * omt);
      const float ldv = __logf(dnum) - 2.f * __logf(den);

      const bool inside = (xv >= -3.f) && (xv <= 3.f);
      xs[row][d] = inside ? yv : xv;        // z in-place (same owner lane)
      ldr[reg] += inside ? ldv : 0.f;
    }
  }

  // ---- log-det: reduce across the 16 cols (lane bits 0..3) ----
  // With all 4 d-chunks done in-block, this is the COMPLETE 64-d sum.
  #pragma unroll
  for (int mask = 1; mask <= 8; mask <<= 1) {
    #pragma unroll
    for (int reg = 0; reg < 4; ++reg)
      ldr[reg] += __shfl_xor(ldr[reg], mask, 64);
  }
  __syncthreads();   // all xs spline-writes done before z readback

  if (col == 0) {
    #pragma unroll
    for (int reg = 0; reg < 4; ++reg)
      out[(size_t)B * 64 + b0 + mt * 16 + quad * 4 + reg] = ldr[reg];
  }

  // ---- coalesced z write: full 64 columns ----
  #pragma unroll
  for (int u = 0; u < 4; ++u) {
    const int idx = t + u * 256;
    const int rr = idx >> 4, c4 = (idx & 15) * 4;
    const float4 v = make_float4(xs[rr][c4 + 0], xs[rr][c4 + 1],
                                 xs[rr][c4 + 2], xs[rr][c4 + 3]);
    *reinterpret_cast<float4*>(out + (size_t)(b0 + rr) * 64 + c4) = v;
  }
}

extern "C" void kernel_launch(void* const* d_in, const int* in_sizes, int n_in,
                              void* d_out, int out_size, void* d_ws, size_t ws_size,
                              hipStream_t stream) {
  const float* x  = (const float*)d_in[0];
  const float* W1 = (const float*)d_in[1];
  const float* b1 = (const float*)d_in[2];
  const float* W2 = (const float*)d_in[3];
  const float* b2 = (const float*)d_in[4];
  const float* W3 = (const float*)d_in[5];
  const float* b3 = (const float*)d_in[6];
  float* out = (float*)d_out;
  char* ws   = (char*)d_ws;

  float* W1t = (float*)ws;                              // 4096 f
  float* W2t = (float*)(ws + 16384);                    // 2048 f
  unsigned short* Bhi = (unsigned short*)(ws + 24576);  // 47104 u16
  unsigned short* Blo = (unsigned short*)(ws + 118784); // 47104 u16

  const int B = in_sizes[0] / 64;        // 32768

  prep_kernel<<<184, 256, 0, stream>>>(W1, W2, W3, W1t, W2t, Bhi, Blo);

  fused_kernel<<<B / 64, 256, 0, stream>>>(
      x, W1t, b1, W2t, b2, Bhi, Blo, b3, out, B);
}

// Round 2
// 121.824 us; speedup vs baseline: 1.0805x; 1.0696x over previous
//
#include <hip/hip_runtime.h>

#define NM 23        // 3*K - 1, K = 8

typedef short short8 __attribute__((ext_vector_type(8)));
typedef float f32x4 __attribute__((ext_vector_type(4)));

__device__ __forceinline__ float softplus_f(float v) {
  return fmaxf(v, 0.f) + __logf(1.f + __expf(-fabsf(v)));
}

__device__ __forceinline__ unsigned short bf16_rne(float x) {
  unsigned u = __float_as_uint(x);
  u += 0x7FFFu + ((u >> 16) & 1u);
  return (unsigned short)(u >> 16);
}

// ---------------------------------------------------------------------------
// Prep. R16: ALL three layers' weights emitted as MFMA B-fragments (bf16
// hi/lo split), pre-masked. Fragment layout (validated on layer 3):
// B[k][n], n = ntile*16 + (lane&15), k = kstep*32 + (lane>>4)*8 + j,
// stored lane-contiguous 16B at ((ntile*nk + kstep)*64 + lane)*8 + j.
//   W1: N=64 i (4 ntiles), K=64 d (2 ksteps)  -> 4096 elems
//   W2: N=32 j (2 ntiles), K=64 i (2 ksteps)  -> 2048 elems
//   W3: N=1472 (92 ntiles), K=32 (1 kstep)    -> 47104 elems
// ---------------------------------------------------------------------------
__global__ __launch_bounds__(256) void prep_kernel(
    const float* __restrict__ W1, const float* __restrict__ W2,
    const float* __restrict__ W3,
    unsigned short* __restrict__ B1hi, unsigned short* __restrict__ B1lo,
    unsigned short* __restrict__ B2hi, unsigned short* __restrict__ B2lo,
    unsigned short* __restrict__ B3hi, unsigned short* __restrict__ B3lo) {
  const int idx = blockIdx.x * 256 + threadIdx.x;
  const int j = idx & 7, lane = (idx >> 3) & 63;
  const int col = lane & 15, quad = lane >> 4;

  if (idx < 4096) {                     // W1 fragments: nt<4, kt<2
    const int rest = idx >> 9, kt = rest & 1, nt = rest >> 1;
    const int k = kt * 32 + quad * 8 + j;   // d
    const int n = nt * 16 + col;            // i
    const float v = ((n % 63) >= k) ? W1[n * 64 + k] : 0.f;
    const unsigned short h = bf16_rne(v);
    B1hi[idx] = h;
    B1lo[idx] = bf16_rne(v - __uint_as_float(((unsigned)h) << 16));
  }
  if (idx < 2048) {                     // W2 fragments: nt<2, kt<2
    const int rest = idx >> 9, kt = rest & 1, nt = rest >> 1;
    const int k = kt * 32 + quad * 8 + j;   // i
    const int n = nt * 16 + col;            // j
    const float v = ((k % 63) <= n) ? W2[n * 64 + k] : 0.f;
    const unsigned short h = bf16_rne(v);
    B2hi[idx] = h;
    B2lo[idx] = bf16_rne(v - __uint_as_float(((unsigned)h) << 16));
  }
  if (idx < 92 * 64 * 8) {              // W3 fragments (unchanged, validated)
    const int nt = idx >> 9;
    const int n = nt * 16 + col;        // n = m*64 + d
    const int d = n & 63;
    const int k = quad * 8 + j;
    const float v = (k < d) ? W3[(size_t)n * 32 + k] : 0.f;
    const unsigned short h = bf16_rne(v);
    B3hi[idx] = h;
    B3lo[idx] = bf16_rne(v - __uint_as_float(((unsigned)h) << 16));
  }
}

// LDS f32x4 pair -> bf16 hi/lo fragment (src must be 16B-aligned)
__device__ __forceinline__ void cvt_hilo(const float* src, short8& hi,
                                         short8& lo) {
  const f32x4 a0 = *reinterpret_cast<const f32x4*>(src);
  const f32x4 a1 = *reinterpret_cast<const f32x4*>(src + 4);
  const float af[8] = {a0.x, a0.y, a0.z, a0.w, a1.x, a1.y, a1.z, a1.w};
  #pragma unroll
  for (int j = 0; j < 8; ++j) {
    const unsigned short h = bf16_rne(af[j]);
    hi[j] = (short)h;
    lo[j] = (short)bf16_rne(af[j] - __uint_as_float(((unsigned)h) << 16));
  }
}

// ---------------------------------------------------------------------------
// Fused kernel. R16 CHANGE: layers 1 and 2 moved from scalar fmac (1536
// FMA + 128 ds_reads per thread) to MFMA (24 + 12 per wave, bf16 hi/lo
// 3-pass — same validated technique as layer 3). Each wave's h1/h2 rows
// [mt*16, mt*16+16) are produced AND consumed by that wave only, so the
// two inter-layer __syncthreads are dropped (intra-wave ds ordering via
// lgkmcnt suffices); waves drift phase-wise, spreading trans/L2 pressure.
// ---------------------------------------------------------------------------
__global__ __launch_bounds__(256, 2) void fused_kernel(
    const float* __restrict__ x,
    const unsigned short* __restrict__ B1hi,
    const unsigned short* __restrict__ B1lo,
    const float* __restrict__ b1,
    const unsigned short* __restrict__ B2hi,
    const unsigned short* __restrict__ B2lo,
    const float* __restrict__ b2,
    const unsigned short* __restrict__ B3hi,
    const unsigned short* __restrict__ B3lo,
    const float* __restrict__ b3,
    float* __restrict__ out, int B) {
  __shared__ float xs[64][68];     // x in; z in-place (68: 16B-aligned rows)
  __shared__ float h1s[64][68];    // stride 68: 16B-aligned b128 A-frag reads
  __shared__ float h2s[64][36];    // stride 36: 16B-aligned b128 A-frag reads
  __shared__ float b3s[64 * NM];   // all 64 d biases: [d][m]

  const int t = threadIdx.x;
  const int b0 = blockIdx.x * 64;

  // ---- stage x: 64x64, 4 float4/thread, coalesced ----
  #pragma unroll
  for (int u = 0; u < 4; ++u) {
    const int idx = t + u * 256;
    const int rr = idx >> 4, c4 = (idx & 15) * 4;
    const float4 v = *reinterpret_cast<const float4*>(
        x + (size_t)b0 * 64 + (size_t)idx * 4);
    xs[rr][c4 + 0] = v.x; xs[rr][c4 + 1] = v.y;
    xs[rr][c4 + 2] = v.z; xs[rr][c4 + 3] = v.w;
  }
  // ---- stage b3 for all d: b3s[d*NM+m] = b3[m*64 + d] ----
  for (int idx = t; idx < 64 * NM; idx += 256) {
    const int dl = idx / NM, m = idx - dl * NM;
    b3s[idx] = b3[m * 64 + dl];
  }
  __syncthreads();

  const int lane = t & 63;
  const int wv   = __builtin_amdgcn_readfirstlane(t >> 6);  // wave 0..3
  const int mt   = wv;                  // M-tile: rows mt*16..mt*16+15
  const int col  = lane & 15;
  const int quad = lane >> 4;
  const int arow = mt * 16 + col;       // A-fragment row for all 3 layers

  // ---- layer 1 (MFMA): h1[64 rows x 64 i] = relu(x @ W1t + b1) ----
  {
    short8 ahi[2], alo[2];
    #pragma unroll
    for (int kt = 0; kt < 2; ++kt)
      cvt_hilo(&xs[arow][kt * 32 + quad * 8], ahi[kt], alo[kt]);

    #pragma unroll
    for (int nt = 0; nt < 4; ++nt) {
      const float bv = b1[nt * 16 + col];
      f32x4 acc = {bv, bv, bv, bv};
      #pragma unroll
      for (int kt = 0; kt < 2; ++kt) {
        const size_t off = ((size_t)(nt * 2 + kt) * 64 + lane) * 8;
        const short8 bh = *reinterpret_cast<const short8*>(B1hi + off);
        const short8 bl = *reinterpret_cast<const short8*>(B1lo + off);
        acc = __builtin_amdgcn_mfma_f32_16x16x32_bf16(ahi[kt], bh, acc, 0, 0, 0);
        acc = __builtin_amdgcn_mfma_f32_16x16x32_bf16(alo[kt], bh, acc, 0, 0, 0);
        acc = __builtin_amdgcn_mfma_f32_16x16x32_bf16(ahi[kt], bl, acc, 0, 0, 0);
      }
      #pragma unroll
      for (int reg = 0; reg < 4; ++reg)
        h1s[mt * 16 + quad * 4 + reg][nt * 16 + col] = fmaxf(acc[reg], 0.f);
    }
  }
  // no barrier: this wave's h1 rows are consumed by this wave only

  // ---- layer 2 (MFMA): h2[64 rows x 32 j] = relu(h1 @ W2t + b2) ----
  {
    short8 ahi[2], alo[2];
    #pragma unroll
    for (int kt = 0; kt < 2; ++kt)
      cvt_hilo(&h1s[arow][kt * 32 + quad * 8], ahi[kt], alo[kt]);

    #pragma unroll
    for (int nt = 0; nt < 2; ++nt) {
      const float bv = b2[nt * 16 + col];
      f32x4 acc = {bv, bv, bv, bv};
      #pragma unroll
      for (int kt = 0; kt < 2; ++kt) {
        const size_t off = ((size_t)(nt * 2 + kt) * 64 + lane) * 8;
        const short8 bh = *reinterpret_cast<const short8*>(B2hi + off);
        const short8 bl = *reinterpret_cast<const short8*>(B2lo + off);
        acc = __builtin_amdgcn_mfma_f32_16x16x32_bf16(ahi[kt], bh, acc, 0, 0, 0);
        acc = __builtin_amdgcn_mfma_f32_16x16x32_bf16(alo[kt], bh, acc, 0, 0, 0);
        acc = __builtin_amdgcn_mfma_f32_16x16x32_bf16(ahi[kt], bl, acc, 0, 0, 0);
      }
      #pragma unroll
      for (int reg = 0; reg < 4; ++reg)
        h2s[mt * 16 + quad * 4 + reg][nt * 16 + col] = fmaxf(acc[reg], 0.f);
    }
  }
  // no barrier: this wave's h2 rows are consumed by this wave only

  // ---- MFMA layer 3 + spline ----
  // A fragment: A[m=lane&15][k=quad*8+j] from h2, bf16 hi/lo split
  short8 ahi, alo;
  cvt_hilo(&h2s[arow][quad * 8], ahi, alo);

  float ldr[4] = {0.f, 0.f, 0.f, 0.f};

  #pragma unroll 1
  for (int jj = 0; jj < 4; ++jj) {
    const int dc = jj;                                    // d-chunk 0..3
    const int d  = dc * 16 + col;                         // this lane's d

    // bias pre-folded into accumulator init (C = A*B + bias)
    f32x4 acc[NM];
    #pragma unroll
    for (int m = 0; m < NM; ++m) {
      const float bv = b3s[d * NM + m];
      acc[m] = (f32x4){bv, bv, bv, bv};
    }
    #pragma unroll
    for (int m = 0; m < NM; ++m) {
      const int nt = 4 * m + dc;
      const size_t off = ((size_t)nt * 64 + lane) * 8;
      const short8 bh = *reinterpret_cast<const short8*>(B3hi + off);
      const short8 bl = *reinterpret_cast<const short8*>(B3lo + off);
      acc[m] = __builtin_amdgcn_mfma_f32_16x16x32_bf16(ahi, bh, acc[m], 0, 0, 0);
      acc[m] = __builtin_amdgcn_mfma_f32_16x16x32_bf16(alo, bh, acc[m], 0, 0, 0);
      acc[m] = __builtin_amdgcn_mfma_f32_16x16x32_bf16(ahi, bl, acc[m], 0, 0, 0);
    }

    // spline: 4 rows per lane (C rows quad*4+reg), this lane's d
    #pragma unroll
    for (int reg = 0; reg < 4; ++reg) {
      const int row = mt * 16 + quad * 4 + reg;

      float p[NM];
      #pragma unroll
      for (int m = 0; m < NM; ++m) p[m] = acc[m][reg];

      const float xv = xs[row][d];
      const float xc = fminf(fmaxf(xv, -3.f), 3.f);

      float mw = p[0];
      #pragma unroll
      for (int k = 1; k < 8; ++k) mw = fmaxf(mw, p[k]);
      float ew[8], sw = 0.f;
      #pragma unroll
      for (int k = 0; k < 8; ++k) { ew[k] = __expf(p[k] - mw); sw += ew[k]; }
      const float invw = 1.f / sw;

      float mh = p[8];
      #pragma unroll
      for (int k = 1; k < 8; ++k) mh = fmaxf(mh, p[8 + k]);
      float eh[8], sh = 0.f;
      #pragma unroll
      for (int k = 0; k < 8; ++k) { eh[k] = __expf(p[8 + k] - mh); sh += eh[k]; }
      const float invh = 1.f / sh;

      const float WSC = 1.0f - 1e-3f * 8.0f;
      float cumw[9], cumh[9];
      cumw[0] = -3.f; cumh[0] = -3.f;
      float cw = 0.f, ch = 0.f;
      #pragma unroll
      for (int k = 0; k < 7; ++k) {
        cw += 1e-3f + WSC * (ew[k] * invw);
        ch += 1e-3f + WSC * (eh[k] * invh);
        cumw[k + 1] = fmaf(6.f, cw, -3.f);
        cumh[k + 1] = fmaf(6.f, ch, -3.f);
      }
      cumw[8] = 3.f; cumh[8] = 3.f;

      float derivs[9];
      derivs[0] = 1.f; derivs[8] = 1.f;
      #pragma unroll
      for (int k = 0; k < 7; ++k) derivs[k + 1] = 1e-3f + softplus_f(p[16 + k]);

      float xk = cumw[0], xk1 = cumw[1];
      float yk = cumh[0], yk1 = cumh[1];
      float dk = derivs[0], dk1 = derivs[1];
      #pragma unroll
      for (int k = 1; k < 8; ++k) {
        const bool s = xc >= cumw[k] + 1e-6f;
        xk  = s ? cumw[k]       : xk;
        xk1 = s ? cumw[k + 1]   : xk1;
        yk  = s ? cumh[k]       : yk;
        yk1 = s ? cumh[k + 1]   : yk1;
        dk  = s ? derivs[k]     : dk;
        dk1 = s ? derivs[k + 1] : dk1;
      }

      const float wk = xk1 - xk, hk = yk1 - yk;
      const float invwk = 1.f / wk;
      const float delta = hk * invwk;
      const float theta = (xc - xk) * invwk;
      const float omt = 1.f - theta;
      const float tt = theta * omt;
      const float th2 = theta * theta;
      const float num = hk * (delta * th2 + dk * tt);
      const float den = delta + (dk + dk1 - 2.f * delta) * tt;
      const float yv = yk + num / den;
      const float dnum = delta * delta * (dk1 * th2 + 2.f * delta * tt + dk * omt * omt);
      const float ldv = __logf(dnum) - 2.f * __logf(den);

      const bool inside = (xv >= -3.f) && (xv <= 3.f);
      xs[row][d] = inside ? yv : xv;        // z in-place (same owner lane)
      ldr[reg] += inside ? ldv : 0.f;
    }
  }

  // ---- log-det: reduce across the 16 cols (lane bits 0..3) ----
  // All 4 d-chunks done in-block => COMPLETE 64-d sum.
  #pragma unroll
  for (int mask = 1; mask <= 8; mask <<= 1) {
    #pragma unroll
    for (int reg = 0; reg < 4; ++reg)
      ldr[reg] += __shfl_xor(ldr[reg], mask, 64);
  }
  __syncthreads();   // all xs spline-writes done before z readback

  if (col == 0) {
    #pragma unroll
    for (int reg = 0; reg < 4; ++reg)
      out[(size_t)B * 64 + b0 + mt * 16 + quad * 4 + reg] = ldr[reg];
  }

  // ---- coalesced z write: full 64 columns ----
  #pragma unroll
  for (int u = 0; u < 4; ++u) {
    const int idx = t + u * 256;
    const int rr = idx >> 4, c4 = (idx & 15) * 4;
    const float4 v = make_float4(xs[rr][c4 + 0], xs[rr][c4 + 1],
                                 xs[rr][c4 + 2], xs[rr][c4 + 3]);
    *reinterpret_cast<float4*>(out + (size_t)(b0 + rr) * 64 + c4) = v;
  }
}

extern "C" void kernel_launch(void* const* d_in, const int* in_sizes, int n_in,
                              void* d_out, int out_size, void* d_ws, size_t ws_size,
                              hipStream_t stream) {
  const float* x  = (const float*)d_in[0];
  const float* W1 = (const float*)d_in[1];
  const float* b1 = (const float*)d_in[2];
  const float* W2 = (const float*)d_in[3];
  const float* b2 = (const float*)d_in[4];
  const float* W3 = (const float*)d_in[5];
  const float* b3 = (const float*)d_in[6];
  float* out = (float*)d_out;
  char* ws   = (char*)d_ws;

  unsigned short* B1hi = (unsigned short*)(ws);           // 4096 u16
  unsigned short* B1lo = (unsigned short*)(ws + 8192);    // 4096 u16
  unsigned short* B2hi = (unsigned short*)(ws + 16384);   // 2048 u16
  unsigned short* B2lo = (unsigned short*)(ws + 20480);   // 2048 u16
  unsigned short* B3hi = (unsigned short*)(ws + 24576);   // 47104 u16
  unsigned short* B3lo = (unsigned short*)(ws + 118784);  // 47104 u16

  const int B = in_sizes[0] / 64;        // 32768

  prep_kernel<<<184, 256, 0, stream>>>(W1, W2, W3, B1hi, B1lo, B2hi, B2lo,
                                       B3hi, B3lo);

  fused_kernel<<<B / 64, 256, 0, stream>>>(
      x, B1hi, B1lo, b1, B2hi, B2lo, b2, B3hi, B3lo, b3, out, B);
}

// Round 3
// 118.440 us; speedup vs baseline: 1.1114x; 1.0286x over previous
//
#include <hip/hip_runtime.h>

#define NM 23        // 3*K - 1, K = 8

typedef short short8 __attribute__((ext_vector_type(8)));
typedef float f32x4 __attribute__((ext_vector_type(4)));

__device__ __forceinline__ float softplus_f(float v) {
  return fmaxf(v, 0.f) + __logf(1.f + __expf(-fabsf(v)));
}

__device__ __forceinline__ float fastrcp(float v) {
  return __builtin_amdgcn_rcpf(v);   // v_rcp_f32, ~1-2 ulp; inputs here are
}                                    // strictly positive and well-scaled

__device__ __forceinline__ unsigned short bf16_rne(float x) {
  unsigned u = __float_as_uint(x);
  u += 0x7FFFu + ((u >> 16) & 1u);
  return (unsigned short)(u >> 16);
}

// ---------------------------------------------------------------------------
// Prep. R16: ALL three layers' weights emitted as MFMA B-fragments (bf16
// hi/lo split), pre-masked. Fragment layout (validated on layer 3):
// B[k][n], n = ntile*16 + (lane&15), k = kstep*32 + (lane>>4)*8 + j,
// stored lane-contiguous 16B at ((ntile*nk + kstep)*64 + lane)*8 + j.
//   W1: N=64 i (4 ntiles), K=64 d (2 ksteps)  -> 4096 elems
//   W2: N=32 j (2 ntiles), K=64 i (2 ksteps)  -> 2048 elems
//   W3: N=1472 (92 ntiles), K=32 (1 kstep)    -> 47104 elems
// ---------------------------------------------------------------------------
__global__ __launch_bounds__(256) void prep_kernel(
    const float* __restrict__ W1, const float* __restrict__ W2,
    const float* __restrict__ W3,
    unsigned short* __restrict__ B1hi, unsigned short* __restrict__ B1lo,
    unsigned short* __restrict__ B2hi, unsigned short* __restrict__ B2lo,
    unsigned short* __restrict__ B3hi, unsigned short* __restrict__ B3lo) {
  const int idx = blockIdx.x * 256 + threadIdx.x;
  const int j = idx & 7, lane = (idx >> 3) & 63;
  const int col = lane & 15, quad = lane >> 4;

  if (idx < 4096) {                     // W1 fragments: nt<4, kt<2
    const int rest = idx >> 9, kt = rest & 1, nt = rest >> 1;
    const int k = kt * 32 + quad * 8 + j;   // d
    const int n = nt * 16 + col;            // i
    const float v = ((n % 63) >= k) ? W1[n * 64 + k] : 0.f;
    const unsigned short h = bf16_rne(v);
    B1hi[idx] = h;
    B1lo[idx] = bf16_rne(v - __uint_as_float(((unsigned)h) << 16));
  }
  if (idx < 2048) {                     // W2 fragments: nt<2, kt<2
    const int rest = idx >> 9, kt = rest & 1, nt = rest >> 1;
    const int k = kt * 32 + quad * 8 + j;   // i
    const int n = nt * 16 + col;            // j
    const float v = ((k % 63) <= n) ? W2[n * 64 + k] : 0.f;
    const unsigned short h = bf16_rne(v);
    B2hi[idx] = h;
    B2lo[idx] = bf16_rne(v - __uint_as_float(((unsigned)h) << 16));
  }
  if (idx < 92 * 64 * 8) {              // W3 fragments (unchanged, validated)
    const int nt = idx >> 9;
    const int n = nt * 16 + col;        // n = m*64 + d
    const int d = n & 63;
    const int k = quad * 8 + j;
    const float v = (k < d) ? W3[(size_t)n * 32 + k] : 0.f;
    const unsigned short h = bf16_rne(v);
    B3hi[idx] = h;
    B3lo[idx] = bf16_rne(v - __uint_as_float(((unsigned)h) << 16));
  }
}

// LDS f32x4 pair -> bf16 hi/lo fragment (src must be 16B-aligned)
__device__ __forceinline__ void cvt_hilo(const float* src, short8& hi,
                                         short8& lo) {
  const f32x4 a0 = *reinterpret_cast<const f32x4*>(src);
  const f32x4 a1 = *reinterpret_cast<const f32x4*>(src + 4);
  const float af[8] = {a0.x, a0.y, a0.z, a0.w, a1.x, a1.y, a1.z, a1.w};
  #pragma unroll
  for (int j = 0; j < 8; ++j) {
    const unsigned short h = bf16_rne(af[j]);
    hi[j] = (short)h;
    lo[j] = (short)bf16_rne(af[j] - __uint_as_float(((unsigned)h) << 16));
  }
}

// ---------------------------------------------------------------------------
// Fused kernel. R17 CHANGE (spline-only micro-surgery, ~-28% spline VALU):
//   (a) 4 IEEE divisions/point -> v_rcp_f32 (each div was ~10 instrs)
//   (b) softmax max-subtraction dropped (logits bounded |p|<~3; exp is
//       well-conditioned; saves 30 instrs + a serial fmax chain per point)
//   (c) log-det: log(dnum) - 2*log(den) -> log(dnum*r*r) reusing r=rcp(den)
//       (1 trans instead of 2)
// Error budget: rcp rel err ~1e-6 -> ~1e-5 abs on outputs, 3 orders below
// the stable 0.0156 absmax floor (bf16 hi/lo accumulation).
// ---------------------------------------------------------------------------
__global__ __launch_bounds__(256, 2) void fused_kernel(
    const float* __restrict__ x,
    const unsigned short* __restrict__ B1hi,
    const unsigned short* __restrict__ B1lo,
    const float* __restrict__ b1,
    const unsigned short* __restrict__ B2hi,
    const unsigned short* __restrict__ B2lo,
    const float* __restrict__ b2,
    const unsigned short* __restrict__ B3hi,
    const unsigned short* __restrict__ B3lo,
    const float* __restrict__ b3,
    float* __restrict__ out, int B) {
  __shared__ float xs[64][68];     // x in; z in-place (68: 16B-aligned rows)
  __shared__ float h1s[64][68];    // stride 68: 16B-aligned b128 A-frag reads
  __shared__ float h2s[64][36];    // stride 36: 16B-aligned b128 A-frag reads
  __shared__ float b3s[64 * NM];   // all 64 d biases: [d][m]

  const int t = threadIdx.x;
  const int b0 = blockIdx.x * 64;

  // ---- stage x: 64x64, 4 float4/thread, coalesced ----
  #pragma unroll
  for (int u = 0; u < 4; ++u) {
    const int idx = t + u * 256;
    const int rr = idx >> 4, c4 = (idx & 15) * 4;
    const float4 v = *reinterpret_cast<const float4*>(
        x + (size_t)b0 * 64 + (size_t)idx * 4);
    xs[rr][c4 + 0] = v.x; xs[rr][c4 + 1] = v.y;
    xs[rr][c4 + 2] = v.z; xs[rr][c4 + 3] = v.w;
  }
  // ---- stage b3 for all d: b3s[d*NM+m] = b3[m*64 + d] ----
  for (int idx = t; idx < 64 * NM; idx += 256) {
    const int dl = idx / NM, m = idx - dl * NM;
    b3s[idx] = b3[m * 64 + dl];
  }
  __syncthreads();

  const int lane = t & 63;
  const int wv   = __builtin_amdgcn_readfirstlane(t >> 6);  // wave 0..3
  const int mt   = wv;                  // M-tile: rows mt*16..mt*16+15
  const int col  = lane & 15;
  const int quad = lane >> 4;
  const int arow = mt * 16 + col;       // A-fragment row for all 3 layers

  // ---- layer 1 (MFMA): h1[64 rows x 64 i] = relu(x @ W1t + b1) ----
  {
    short8 ahi[2], alo[2];
    #pragma unroll
    for (int kt = 0; kt < 2; ++kt)
      cvt_hilo(&xs[arow][kt * 32 + quad * 8], ahi[kt], alo[kt]);

    #pragma unroll
    for (int nt = 0; nt < 4; ++nt) {
      const float bv = b1[nt * 16 + col];
      f32x4 acc = {bv, bv, bv, bv};
      #pragma unroll
      for (int kt = 0; kt < 2; ++kt) {
        const size_t off = ((size_t)(nt * 2 + kt) * 64 + lane) * 8;
        const short8 bh = *reinterpret_cast<const short8*>(B1hi + off);
        const short8 bl = *reinterpret_cast<const short8*>(B1lo + off);
        acc = __builtin_amdgcn_mfma_f32_16x16x32_bf16(ahi[kt], bh, acc, 0, 0, 0);
        acc = __builtin_amdgcn_mfma_f32_16x16x32_bf16(alo[kt], bh, acc, 0, 0, 0);
        acc = __builtin_amdgcn_mfma_f32_16x16x32_bf16(ahi[kt], bl, acc, 0, 0, 0);
      }
      #pragma unroll
      for (int reg = 0; reg < 4; ++reg)
        h1s[mt * 16 + quad * 4 + reg][nt * 16 + col] = fmaxf(acc[reg], 0.f);
    }
  }
  // no barrier: this wave's h1 rows are consumed by this wave only

  // ---- layer 2 (MFMA): h2[64 rows x 32 j] = relu(h1 @ W2t + b2) ----
  {
    short8 ahi[2], alo[2];
    #pragma unroll
    for (int kt = 0; kt < 2; ++kt)
      cvt_hilo(&h1s[arow][kt * 32 + quad * 8], ahi[kt], alo[kt]);

    #pragma unroll
    for (int nt = 0; nt < 2; ++nt) {
      const float bv = b2[nt * 16 + col];
      f32x4 acc = {bv, bv, bv, bv};
      #pragma unroll
      for (int kt = 0; kt < 2; ++kt) {
        const size_t off = ((size_t)(nt * 2 + kt) * 64 + lane) * 8;
        const short8 bh = *reinterpret_cast<const short8*>(B2hi + off);
        const short8 bl = *reinterpret_cast<const short8*>(B2lo + off);
        acc = __builtin_amdgcn_mfma_f32_16x16x32_bf16(ahi[kt], bh, acc, 0, 0, 0);
        acc = __builtin_amdgcn_mfma_f32_16x16x32_bf16(alo[kt], bh, acc, 0, 0, 0);
        acc = __builtin_amdgcn_mfma_f32_16x16x32_bf16(ahi[kt], bl, acc, 0, 0, 0);
      }
      #pragma unroll
      for (int reg = 0; reg < 4; ++reg)
        h2s[mt * 16 + quad * 4 + reg][nt * 16 + col] = fmaxf(acc[reg], 0.f);
    }
  }
  // no barrier: this wave's h2 rows are consumed by this wave only

  // ---- MFMA layer 3 + spline ----
  // A fragment: A[m=lane&15][k=quad*8+j] from h2, bf16 hi/lo split
  short8 ahi, alo;
  cvt_hilo(&h2s[arow][quad * 8], ahi, alo);

  float ldr[4] = {0.f, 0.f, 0.f, 0.f};

  #pragma unroll 1
  for (int jj = 0; jj < 4; ++jj) {
    const int dc = jj;                                    // d-chunk 0..3
    const int d  = dc * 16 + col;                         // this lane's d

    // bias pre-folded into accumulator init (C = A*B + bias)
    f32x4 acc[NM];
    #pragma unroll
    for (int m = 0; m < NM; ++m) {
      const float bv = b3s[d * NM + m];
      acc[m] = (f32x4){bv, bv, bv, bv};
    }
    #pragma unroll
    for (int m = 0; m < NM; ++m) {
      const int nt = 4 * m + dc;
      const size_t off = ((size_t)nt * 64 + lane) * 8;
      const short8 bh = *reinterpret_cast<const short8*>(B3hi + off);
      const short8 bl = *reinterpret_cast<const short8*>(B3lo + off);
      acc[m] = __builtin_amdgcn_mfma_f32_16x16x32_bf16(ahi, bh, acc[m], 0, 0, 0);
      acc[m] = __builtin_amdgcn_mfma_f32_16x16x32_bf16(alo, bh, acc[m], 0, 0, 0);
      acc[m] = __builtin_amdgcn_mfma_f32_16x16x32_bf16(ahi, bl, acc[m], 0, 0, 0);
    }

    // spline: 4 rows per lane (C rows quad*4+reg), this lane's d
    #pragma unroll
    for (int reg = 0; reg < 4; ++reg) {
      const int row = mt * 16 + quad * 4 + reg;

      float p[NM];
      #pragma unroll
      for (int m = 0; m < NM; ++m) p[m] = acc[m][reg];

      const float xv = xs[row][d];
      const float xc = fminf(fmaxf(xv, -3.f), 3.f);

      // softmax without max-subtraction: logits bounded, exp well-conditioned
      float ew[8], sw = 0.f;
      #pragma unroll
      for (int k = 0; k < 8; ++k) { ew[k] = __expf(p[k]); sw += ew[k]; }
      const float invw = fastrcp(sw);

      float eh[8], sh = 0.f;
      #pragma unroll
      for (int k = 0; k < 8; ++k) { eh[k] = __expf(p[8 + k]); sh += eh[k]; }
      const float invh = fastrcp(sh);

      const float WSC = 1.0f - 1e-3f * 8.0f;
      float cumw[9], cumh[9];
      cumw[0] = -3.f; cumh[0] = -3.f;
      float cw = 0.f, ch = 0.f;
      #pragma unroll
      for (int k = 0; k < 7; ++k) {
        cw += 1e-3f + WSC * (ew[k] * invw);
        ch += 1e-3f + WSC * (eh[k] * invh);
        cumw[k + 1] = fmaf(6.f, cw, -3.f);
        cumh[k + 1] = fmaf(6.f, ch, -3.f);
      }
      cumw[8] = 3.f; cumh[8] = 3.f;

      float derivs[9];
      derivs[0] = 1.f; derivs[8] = 1.f;
      #pragma unroll
      for (int k = 0; k < 7; ++k) derivs[k + 1] = 1e-3f + softplus_f(p[16 + k]);

      float xk = cumw[0], xk1 = cumw[1];
      float yk = cumh[0], yk1 = cumh[1];
      float dk = derivs[0], dk1 = derivs[1];
      #pragma unroll
      for (int k = 1; k < 8; ++k) {
        const bool s = xc >= cumw[k] + 1e-6f;
        xk  = s ? cumw[k]       : xk;
        xk1 = s ? cumw[k + 1]   : xk1;
        yk  = s ? cumh[k]       : yk;
        yk1 = s ? cumh[k + 1]   : yk1;
        dk  = s ? derivs[k]     : dk;
        dk1 = s ? derivs[k + 1] : dk1;
      }

      const float wk = xk1 - xk, hk = yk1 - yk;
      const float invwk = fastrcp(wk);
      const float delta = hk * invwk;
      const float theta = (xc - xk) * invwk;
      const float omt = 1.f - theta;
      const float tt = theta * omt;
      const float th2 = theta * theta;
      const float num = hk * (delta * th2 + dk * tt);
      const float den = delta + (dk + dk1 - 2.f * delta) * tt;
      const float rden = fastrcp(den);
      const float yv = yk + num * rden;
      const float dnum = delta * delta * (dk1 * th2 + 2.f * delta * tt + dk * omt * omt);
      const float ldv = __logf(dnum * rden * rden);   // log(dnum) - 2 log(den)

      const bool inside = (xv >= -3.f) && (xv <= 3.f);
      xs[row][d] = inside ? yv : xv;        // z in-place (same owner lane)
      ldr[reg] += inside ? ldv : 0.f;
    }
  }

  // ---- log-det: reduce across the 16 cols (lane bits 0..3) ----
  // All 4 d-chunks done in-block => COMPLETE 64-d sum.
  #pragma unroll
  for (int mask = 1; mask <= 8; mask <<= 1) {
    #pragma unroll
    for (int reg = 0; reg < 4; ++reg)
      ldr[reg] += __shfl_xor(ldr[reg], mask, 64);
  }
  __syncthreads();   // all xs spline-writes done before z readback

  if (col == 0) {
    #pragma unroll
    for (int reg = 0; reg < 4; ++reg)
      out[(size_t)B * 64 + b0 + mt * 16 + quad * 4 + reg] = ldr[reg];
  }

  // ---- coalesced z write: full 64 columns ----
  #pragma unroll
  for (int u = 0; u < 4; ++u) {
    const int idx = t + u * 256;
    const int rr = idx >> 4, c4 = (idx & 15) * 4;
    const float4 v = make_float4(xs[rr][c4 + 0], xs[rr][c4 + 1],
                                 xs[rr][c4 + 2], xs[rr][c4 + 3]);
    *reinterpret_cast<float4*>(out + (size_t)(b0 + rr) * 64 + c4) = v;
  }
}

extern "C" void kernel_launch(void* const* d_in, const int* in_sizes, int n_in,
                              void* d_out, int out_size, void* d_ws, size_t ws_size,
                              hipStream_t stream) {
  const float* x  = (const float*)d_in[0];
  const float* W1 = (const float*)d_in[1];
  const float* b1 = (const float*)d_in[2];
  const float* W2 = (const float*)d_in[3];
  const float* b2 = (const float*)d_in[4];
  const float* W3 = (const float*)d_in[5];
  const float* b3 = (const float*)d_in[6];
  float* out = (float*)d_out;
  char* ws   = (char*)d_ws;

  unsigned short* B1hi = (unsigned short*)(ws);           // 4096 u16
  unsigned short* B1lo = (unsigned short*)(ws + 8192);    // 4096 u16
  unsigned short* B2hi = (unsigned short*)(ws + 16384);   // 2048 u16
  unsigned short* B2lo = (unsigned short*)(ws + 20480);   // 2048 u16
  unsigned short* B3hi = (unsigned short*)(ws + 24576);   // 47104 u16
  unsigned short* B3lo = (unsigned short*)(ws + 118784);  // 47104 u16

  const int B = in_sizes[0] / 64;        // 32768

  prep_kernel<<<184, 256, 0, stream>>>(W1, W2, W3, B1hi, B1lo, B2hi, B2lo,
                                       B3hi, B3lo);

  fused_kernel<<<B / 64, 256, 0, stream>>>(
      x, B1hi, B1lo, b1, B2hi, B2lo, b2, B3hi, B3lo, b3, out, B);
}

// Round 4
// 118.185 us; speedup vs baseline: 1.1138x; 1.0022x over previous
//
#include <hip/hip_runtime.h>

#define NM 23        // 3*K - 1, K = 8

typedef short short8 __attribute__((ext_vector_type(8)));
typedef float f32x4 __attribute__((ext_vector_type(4)));

__device__ __forceinline__ float softplus_f(float v) {
  return fmaxf(v, 0.f) + __logf(1.f + __expf(-fabsf(v)));
}

__device__ __forceinline__ float fastrcp(float v) {
  return __builtin_amdgcn_rcpf(v);   // v_rcp_f32, ~1-2 ulp
}

__device__ __forceinline__ unsigned short bf16_rne(float x) {
  unsigned u = __float_as_uint(x);
  u += 0x7FFFu + ((u >> 16) & 1u);
  return (unsigned short)(u >> 16);
}

// ---------------------------------------------------------------------------
// Prep (unchanged, validated). Fragment layout:
// B[k][n], n = ntile*16 + (lane&15), k = kstep*32 + (lane>>4)*8 + j,
// stored lane-contiguous 16B at ((ntile*nk + kstep)*64 + lane)*8 + j.
// ---------------------------------------------------------------------------
__global__ __launch_bounds__(256) void prep_kernel(
    const float* __restrict__ W1, const float* __restrict__ W2,
    const float* __restrict__ W3,
    unsigned short* __restrict__ B1hi, unsigned short* __restrict__ B1lo,
    unsigned short* __restrict__ B2hi, unsigned short* __restrict__ B2lo,
    unsigned short* __restrict__ B3hi, unsigned short* __restrict__ B3lo) {
  const int idx = blockIdx.x * 256 + threadIdx.x;
  const int j = idx & 7, lane = (idx >> 3) & 63;
  const int col = lane & 15, quad = lane >> 4;

  if (idx < 4096) {                     // W1 fragments: nt<4, kt<2
    const int rest = idx >> 9, kt = rest & 1, nt = rest >> 1;
    const int k = kt * 32 + quad * 8 + j;   // d
    const int n = nt * 16 + col;            // i
    const float v = ((n % 63) >= k) ? W1[n * 64 + k] : 0.f;
    const unsigned short h = bf16_rne(v);
    B1hi[idx] = h;
    B1lo[idx] = bf16_rne(v - __uint_as_float(((unsigned)h) << 16));
  }
  if (idx < 2048) {                     // W2 fragments: nt<2, kt<2
    const int rest = idx >> 9, kt = rest & 1, nt = rest >> 1;
    const int k = kt * 32 + quad * 8 + j;   // i
    const int n = nt * 16 + col;            // j
    const float v = ((k % 63) <= n) ? W2[n * 64 + k] : 0.f;
    const unsigned short h = bf16_rne(v);
    B2hi[idx] = h;
    B2lo[idx] = bf16_rne(v - __uint_as_float(((unsigned)h) << 16));
  }
  if (idx < 92 * 64 * 8) {              // W3 fragments
    const int nt = idx >> 9;
    const int n = nt * 16 + col;        // n = m*64 + d
    const int d = n & 63;
    const int k = quad * 8 + j;
    const float v = (k < d) ? W3[(size_t)n * 32 + k] : 0.f;
    const unsigned short h = bf16_rne(v);
    B3hi[idx] = h;
    B3lo[idx] = bf16_rne(v - __uint_as_float(((unsigned)h) << 16));
  }
}

// f32x4 pair (LDS or global, 16B-aligned) -> bf16 hi/lo fragment
__device__ __forceinline__ void cvt_hilo(const float* src, short8& hi,
                                         short8& lo) {
  const f32x4 a0 = *reinterpret_cast<const f32x4*>(src);
  const f32x4 a1 = *reinterpret_cast<const f32x4*>(src + 4);
  const float af[8] = {a0.x, a0.y, a0.z, a0.w, a1.x, a1.y, a1.z, a1.w};
  #pragma unroll
  for (int j = 0; j < 8; ++j) {
    const unsigned short h = bf16_rne(af[j]);
    hi[j] = (short)h;
    lo[j] = (short)bf16_rne(af[j] - __uint_as_float(((unsigned)h) << 16));
  }
}

// ---------------------------------------------------------------------------
// Fused kernel. R18 CHANGE (occupancy 2x — the R17 post-mortem showed a
// latency-bound kernel at 2 waves/SIMD, reg bucket 256 from acc[23]=92 AGPR):
//   (a) layer-3 m-GROUP SPLIT: widths / heights / derivs computed with one
//       reusable acc[8] (32 regs). Bin-select runs per group via idx
//       (identical select semantics); only {xc,idx,xk,wk,yk,hk} persist.
//   (b) derivs: select the TWO needed logits via idx, then softplus x2
//       (was softplus x7).
//   (c) xs LDS dropped: x read direct from global (L2-hot, 64B-coalesced
//       per quad), z stored direct to global. LDS 50K -> 31.8K, barriers
//       2 -> 1 (b3s stage only).
//   (d) __launch_bounds__(256,4): force <=128 regs -> 16 waves/CU.
// z/ld arithmetic is bit-identical to R17 (same MFMA order, same selects).
// ---------------------------------------------------------------------------
__global__ __launch_bounds__(256, 4) void fused_kernel(
    const float* __restrict__ x,
    const unsigned short* __restrict__ B1hi,
    const unsigned short* __restrict__ B1lo,
    const float* __restrict__ b1,
    const unsigned short* __restrict__ B2hi,
    const unsigned short* __restrict__ B2lo,
    const float* __restrict__ b2,
    const unsigned short* __restrict__ B3hi,
    const unsigned short* __restrict__ B3lo,
    const float* __restrict__ b3,
    float* __restrict__ out, int B) {
  __shared__ float h1s[64][68];    // stride 68: 16B-aligned b128 A-frag reads
  __shared__ float h2s[64][36];    // stride 36: 16B-aligned b128 A-frag reads
  __shared__ float b3s[64 * NM];   // all 64 d biases: [d][m]

  const int t = threadIdx.x;
  const int b0 = blockIdx.x * 64;

  // ---- stage b3 for all d: b3s[d*NM+m] = b3[m*64 + d] ----
  for (int idx = t; idx < 64 * NM; idx += 256) {
    const int dl = idx / NM, m = idx - dl * NM;
    b3s[idx] = b3[m * 64 + dl];
  }
  __syncthreads();                 // the only block-wide barrier

  const int lane = t & 63;
  const int wv   = __builtin_amdgcn_readfirstlane(t >> 6);  // wave 0..3
  const int mt   = wv;                  // M-tile: rows mt*16..mt*16+15
  const int col  = lane & 15;
  const int quad = lane >> 4;
  const int arow = mt * 16 + col;       // A-fragment row for all 3 layers

  // ---- layer 1 (MFMA): A-frags straight from global x ----
  {
    const float* xrow = x + (size_t)(b0 + arow) * 64;
    short8 ahi[2], alo[2];
    #pragma unroll
    for (int kt = 0; kt < 2; ++kt)
      cvt_hilo(xrow + kt * 32 + quad * 8, ahi[kt], alo[kt]);

    #pragma unroll
    for (int nt = 0; nt < 4; ++nt) {
      const float bv = b1[nt * 16 + col];
      f32x4 acc = {bv, bv, bv, bv};
      #pragma unroll
      for (int kt = 0; kt < 2; ++kt) {
        const size_t off = ((size_t)(nt * 2 + kt) * 64 + lane) * 8;
        const short8 bh = *reinterpret_cast<const short8*>(B1hi + off);
        const short8 bl = *reinterpret_cast<const short8*>(B1lo + off);
        acc = __builtin_amdgcn_mfma_f32_16x16x32_bf16(ahi[kt], bh, acc, 0, 0, 0);
        acc = __builtin_amdgcn_mfma_f32_16x16x32_bf16(alo[kt], bh, acc, 0, 0, 0);
        acc = __builtin_amdgcn_mfma_f32_16x16x32_bf16(ahi[kt], bl, acc, 0, 0, 0);
      }
      #pragma unroll
      for (int reg = 0; reg < 4; ++reg)
        h1s[mt * 16 + quad * 4 + reg][nt * 16 + col] = fmaxf(acc[reg], 0.f);
    }
  }
  // no barrier: this wave's h1 rows are consumed by this wave only

  // ---- layer 2 (MFMA): h2 = relu(h1 @ W2t + b2) ----
  {
    short8 ahi[2], alo[2];
    #pragma unroll
    for (int kt = 0; kt < 2; ++kt)
      cvt_hilo(&h1s[arow][kt * 32 + quad * 8], ahi[kt], alo[kt]);

    #pragma unroll
    for (int nt = 0; nt < 2; ++nt) {
      const float bv = b2[nt * 16 + col];
      f32x4 acc = {bv, bv, bv, bv};
      #pragma unroll
      for (int kt = 0; kt < 2; ++kt) {
        const size_t off = ((size_t)(nt * 2 + kt) * 64 + lane) * 8;
        const short8 bh = *reinterpret_cast<const short8*>(B2hi + off);
        const short8 bl = *reinterpret_cast<const short8*>(B2lo + off);
        acc = __builtin_amdgcn_mfma_f32_16x16x32_bf16(ahi[kt], bh, acc, 0, 0, 0);
        acc = __builtin_amdgcn_mfma_f32_16x16x32_bf16(alo[kt], bh, acc, 0, 0, 0);
        acc = __builtin_amdgcn_mfma_f32_16x16x32_bf16(ahi[kt], bl, acc, 0, 0, 0);
      }
      #pragma unroll
      for (int reg = 0; reg < 4; ++reg)
        h2s[mt * 16 + quad * 4 + reg][nt * 16 + col] = fmaxf(acc[reg], 0.f);
    }
  }
  // no barrier: this wave's h2 rows are consumed by this wave only

  // ---- layer 3 (grouped MFMA) + spline ----
  short8 ahi, alo;
  cvt_hilo(&h2s[arow][quad * 8], ahi, alo);

  float ldr[4] = {0.f, 0.f, 0.f, 0.f};
  const float* xg = x + (size_t)b0 * 64;
  float* zg = out + (size_t)b0 * 64;
  const int row0 = mt * 16 + quad * 4;
  const float WSC = 1.0f - 1e-3f * 8.0f;

  #pragma unroll 1
  for (int dc = 0; dc < 4; ++dc) {
    const int d = dc * 16 + col;          // this lane's d

    float xvv[4];
    #pragma unroll
    for (int reg = 0; reg < 4; ++reg)
      xvv[reg] = xg[(size_t)(row0 + reg) * 64 + d];

    float xcv[4], fidx[4], xkv[4], wkv[4], ykv[4], hkv[4];

    // ======== group W: m in [0,8) -> xc, idx, xk, wk ========
    {
      f32x4 acc[8];
      #pragma unroll
      for (int m = 0; m < 8; ++m) {
        const float bv = b3s[d * NM + m];
        acc[m] = (f32x4){bv, bv, bv, bv};
      }
      #pragma unroll
      for (int m = 0; m < 8; ++m) {
        const size_t off = ((size_t)(4 * m + dc) * 64 + lane) * 8;
        const short8 bh = *reinterpret_cast<const short8*>(B3hi + off);
        const short8 bl = *reinterpret_cast<const short8*>(B3lo + off);
        acc[m] = __builtin_amdgcn_mfma_f32_16x16x32_bf16(ahi, bh, acc[m], 0, 0, 0);
        acc[m] = __builtin_amdgcn_mfma_f32_16x16x32_bf16(alo, bh, acc[m], 0, 0, 0);
        acc[m] = __builtin_amdgcn_mfma_f32_16x16x32_bf16(ahi, bl, acc[m], 0, 0, 0);
      }
      #pragma unroll
      for (int reg = 0; reg < 4; ++reg) {
        float ew[8], sw = 0.f;
        #pragma unroll
        for (int k = 0; k < 8; ++k) { ew[k] = __expf(acc[k][reg]); sw += ew[k]; }
        const float invw = fastrcp(sw);
        float cumw[9];
        cumw[0] = -3.f;
        float cw = 0.f;
        #pragma unroll
        for (int k = 0; k < 7; ++k) {
          cw += 1e-3f + WSC * (ew[k] * invw);
          cumw[k + 1] = fmaf(6.f, cw, -3.f);
        }
        cumw[8] = 3.f;

        const float xv = xvv[reg];
        const float xc = fminf(fmaxf(xv, -3.f), 3.f);
        float fi = 0.f, xk = cumw[0], xk1 = cumw[1];
        #pragma unroll
        for (int k = 1; k < 8; ++k) {
          const bool s = xc >= cumw[k] + 1e-6f;
          xk  = s ? cumw[k]     : xk;
          xk1 = s ? cumw[k + 1] : xk1;
          fi  = s ? (float)k    : fi;
        }
        xcv[reg] = xc; fidx[reg] = fi; xkv[reg] = xk; wkv[reg] = xk1 - xk;
      }
    }

    // ======== group H: m in [8,16) -> yk, hk ========
    {
      f32x4 acc[8];
      #pragma unroll
      for (int m = 0; m < 8; ++m) {
        const float bv = b3s[d * NM + (8 + m)];
        acc[m] = (f32x4){bv, bv, bv, bv};
      }
      #pragma unroll
      for (int m = 0; m < 8; ++m) {
        const size_t off = ((size_t)(4 * (8 + m) + dc) * 64 + lane) * 8;
        const short8 bh = *reinterpret_cast<const short8*>(B3hi + off);
        const short8 bl = *reinterpret_cast<const short8*>(B3lo + off);
        acc[m] = __builtin_amdgcn_mfma_f32_16x16x32_bf16(ahi, bh, acc[m], 0, 0, 0);
        acc[m] = __builtin_amdgcn_mfma_f32_16x16x32_bf16(alo, bh, acc[m], 0, 0, 0);
        acc[m] = __builtin_amdgcn_mfma_f32_16x16x32_bf16(ahi, bl, acc[m], 0, 0, 0);
      }
      #pragma unroll
      for (int reg = 0; reg < 4; ++reg) {
        float eh[8], sh = 0.f;
        #pragma unroll
        for (int k = 0; k < 8; ++k) { eh[k] = __expf(acc[k][reg]); sh += eh[k]; }
        const float invh = fastrcp(sh);
        float cumh[9];
        cumh[0] = -3.f;
        float ch = 0.f;
        #pragma unroll
        for (int k = 0; k < 7; ++k) {
          ch += 1e-3f + WSC * (eh[k] * invh);
          cumh[k + 1] = fmaf(6.f, ch, -3.f);
        }
        cumh[8] = 3.f;

        float yk = cumh[0], yk1 = cumh[1];
        #pragma unroll
        for (int k = 1; k < 8; ++k) {
          const bool s = fidx[reg] >= (float)k;
          yk  = s ? cumh[k]     : yk;
          yk1 = s ? cumh[k + 1] : yk1;
        }
        ykv[reg] = yk; hkv[reg] = yk1 - yk;
      }
    }

    // ======== group D: m in [16,23) -> dk, dk1 + final spline ========
    {
      f32x4 acc[7];
      #pragma unroll
      for (int m = 0; m < 7; ++m) {
        const float bv = b3s[d * NM + (16 + m)];
        acc[m] = (f32x4){bv, bv, bv, bv};
      }
      #pragma unroll
      for (int m = 0; m < 7; ++m) {
        const size_t off = ((size_t)(4 * (16 + m) + dc) * 64 + lane) * 8;
        const short8 bh = *reinterpret_cast<const short8*>(B3hi + off);
        const short8 bl = *reinterpret_cast<const short8*>(B3lo + off);
        acc[m] = __builtin_amdgcn_mfma_f32_16x16x32_bf16(ahi, bh, acc[m], 0, 0, 0);
        acc[m] = __builtin_amdgcn_mfma_f32_16x16x32_bf16(alo, bh, acc[m], 0, 0, 0);
        acc[m] = __builtin_amdgcn_mfma_f32_16x16x32_bf16(ahi, bl, acc[m], 0, 0, 0);
      }
      #pragma unroll
      for (int reg = 0; reg < 4; ++reg) {
        float p[7];
        #pragma unroll
        for (int k = 0; k < 7; ++k) p[k] = acc[k][reg];
        const float fi = fidx[reg];

        // dk  = idx==0 ? 1 : 1e-3+sp(p[idx-1]);  pa = p[idx-1] for idx>=1
        // dk1 = idx==7 ? 1 : 1e-3+sp(p[idx]);    pb = p[idx]   for idx<=6
        float pa = p[0], pb = p[0];
        #pragma unroll
        for (int k = 2; k < 8; ++k) pa = (fi >= (float)k) ? p[k - 1] : pa;
        #pragma unroll
        for (int k = 1; k < 7; ++k) pb = (fi >= (float)k) ? p[k] : pb;
        const float spa = 1e-3f + softplus_f(pa);
        const float spb = 1e-3f + softplus_f(pb);
        const float dk  = (fi >= 0.5f) ? spa : 1.f;
        const float dk1 = (fi >= 6.5f) ? 1.f : spb;

        const float xc = xcv[reg], xk = xkv[reg], wk = wkv[reg];
        const float yk = ykv[reg], hk = hkv[reg];
        const float invwk = fastrcp(wk);
        const float delta = hk * invwk;
        const float theta = (xc - xk) * invwk;
        const float omt = 1.f - theta;
        const float tt = theta * omt;
        const float th2 = theta * theta;
        const float num = hk * (delta * th2 + dk * tt);
        const float den = delta + (dk + dk1 - 2.f * delta) * tt;
        const float rden = fastrcp(den);
        const float yv = yk + num * rden;
        const float dnum =
            delta * delta * (dk1 * th2 + 2.f * delta * tt + dk * omt * omt);
        const float ldv = __logf(dnum * rden * rden);

        const float xv = xvv[reg];
        const bool inside = (xv >= -3.f) && (xv <= 3.f);
        zg[(size_t)(row0 + reg) * 64 + d] = inside ? yv : xv;
        ldr[reg] += inside ? ldv : 0.f;
      }
    }
  }

  // ---- log-det: reduce across the 16 cols (lane bits 0..3) ----
  #pragma unroll
  for (int mask = 1; mask <= 8; mask <<= 1) {
    #pragma unroll
    for (int reg = 0; reg < 4; ++reg)
      ldr[reg] += __shfl_xor(ldr[reg], mask, 64);
  }

  if (col == 0) {
    #pragma unroll
    for (int reg = 0; reg < 4; ++reg)
      out[(size_t)B * 64 + b0 + row0 + reg] = ldr[reg];
  }
}

extern "C" void kernel_launch(void* const* d_in, const int* in_sizes, int n_in,
                              void* d_out, int out_size, void* d_ws, size_t ws_size,
                              hipStream_t stream) {
  const float* x  = (const float*)d_in[0];
  const float* W1 = (const float*)d_in[1];
  const float* b1 = (const float*)d_in[2];
  const float* W2 = (const float*)d_in[3];
  const float* b2 = (const float*)d_in[4];
  const float* W3 = (const float*)d_in[5];
  const float* b3 = (const float*)d_in[6];
  float* out = (float*)d_out;
  char* ws   = (char*)d_ws;

  unsigned short* B1hi = (unsigned short*)(ws);           // 4096 u16
  unsigned short* B1lo = (unsigned short*)(ws + 8192);    // 4096 u16
  unsigned short* B2hi = (unsigned short*)(ws + 16384);   // 2048 u16
  unsigned short* B2lo = (unsigned short*)(ws + 20480);   // 2048 u16
  unsigned short* B3hi = (unsigned short*)(ws + 24576);   // 47104 u16
  unsigned short* B3lo = (unsigned short*)(ws + 118784);  // 47104 u16

  const int B = in_sizes[0] / 64;        // 32768

  prep_kernel<<<184, 256, 0, stream>>>(W1, W2, W3, B1hi, B1lo, B2hi, B2lo,
                                       B3hi, B3lo);

  fused_kernel<<<B / 64, 256, 0, stream>>>(
      x, B1hi, B1lo, b1, B2hi, B2lo, b2, B3hi, B3lo, b3, out, B);
}

// Round 5
// 117.489 us; speedup vs baseline: 1.1204x; 1.0059x over previous
//
#include <hip/hip_runtime.h>

#define NM 23        // 3*K - 1, K = 8

typedef short short8 __attribute__((ext_vector_type(8)));
typedef float f32x4 __attribute__((ext_vector_type(4)));

__device__ __forceinline__ float softplus_f(float v) {
  return fmaxf(v, 0.f) + __logf(1.f + __expf(-fabsf(v)));
}

__device__ __forceinline__ float fastrcp(float v) {
  return __builtin_amdgcn_rcpf(v);   // v_rcp_f32, ~1-2 ulp
}

__device__ __forceinline__ unsigned short bf16_rne(float x) {
  unsigned u = __float_as_uint(x);
  u += 0x7FFFu + ((u >> 16) & 1u);
  return (unsigned short)(u >> 16);
}

// ---------------------------------------------------------------------------
// Prep (unchanged, validated). Fragment layout:
// B[k][n], n = ntile*16 + (lane&15), k = kstep*32 + (lane>>4)*8 + j,
// stored lane-contiguous 16B at ((ntile*nk + kstep)*64 + lane)*8 + j.
// ---------------------------------------------------------------------------
__global__ __launch_bounds__(256) void prep_kernel(
    const float* __restrict__ W1, const float* __restrict__ W2,
    const float* __restrict__ W3,
    unsigned short* __restrict__ B1hi, unsigned short* __restrict__ B1lo,
    unsigned short* __restrict__ B2hi, unsigned short* __restrict__ B2lo,
    unsigned short* __restrict__ B3hi, unsigned short* __restrict__ B3lo) {
  const int idx = blockIdx.x * 256 + threadIdx.x;
  const int j = idx & 7, lane = (idx >> 3) & 63;
  const int col = lane & 15, quad = lane >> 4;

  if (idx < 4096) {                     // W1 fragments: nt<4, kt<2
    const int rest = idx >> 9, kt = rest & 1, nt = rest >> 1;
    const int k = kt * 32 + quad * 8 + j;   // d
    const int n = nt * 16 + col;            // i
    const float v = ((n % 63) >= k) ? W1[n * 64 + k] : 0.f;
    const unsigned short h = bf16_rne(v);
    B1hi[idx] = h;
    B1lo[idx] = bf16_rne(v - __uint_as_float(((unsigned)h) << 16));
  }
  if (idx < 2048) {                     // W2 fragments: nt<2, kt<2
    const int rest = idx >> 9, kt = rest & 1, nt = rest >> 1;
    const int k = kt * 32 + quad * 8 + j;   // i
    const int n = nt * 16 + col;            // j
    const float v = ((k % 63) <= n) ? W2[n * 64 + k] : 0.f;
    const unsigned short h = bf16_rne(v);
    B2hi[idx] = h;
    B2lo[idx] = bf16_rne(v - __uint_as_float(((unsigned)h) << 16));
  }
  if (idx < 92 * 64 * 8) {              // W3 fragments
    const int nt = idx >> 9;
    const int n = nt * 16 + col;        // n = m*64 + d
    const int d = n & 63;
    const int k = quad * 8 + j;
    const float v = (k < d) ? W3[(size_t)n * 32 + k] : 0.f;
    const unsigned short h = bf16_rne(v);
    B3hi[idx] = h;
    B3lo[idx] = bf16_rne(v - __uint_as_float(((unsigned)h) << 16));
  }
}

// f32x4 pair (LDS, 16B-aligned) -> bf16 hi/lo fragment
__device__ __forceinline__ void cvt_hilo(const float* src, short8& hi,
                                         short8& lo) {
  const f32x4 a0 = *reinterpret_cast<const f32x4*>(src);
  const f32x4 a1 = *reinterpret_cast<const f32x4*>(src + 4);
  const float af[8] = {a0.x, a0.y, a0.z, a0.w, a1.x, a1.y, a1.z, a1.w};
  #pragma unroll
  for (int j = 0; j < 8; ++j) {
    const unsigned short h = bf16_rne(af[j]);
    hi[j] = (short)h;
    lo[j] = (short)bf16_rne(af[j] - __uint_as_float(((unsigned)h) << 16));
  }
}

// ---------------------------------------------------------------------------
// Fused kernel. R19 CHANGE (R18 post-mortem: direct global z-stores caused
// 6.3x HBM write amplification — WRITE_SIZE 8.3->52.5 MB — cancelling the
// occupancy win. Fix: keep R18's register diet, restore R17's coalesced
// memory pattern):
//   (a) xvv (16 spline x-values/lane) hoisted to REGISTERS before layer 1.
//   (b) xs LDS then hosts x -> h1 -> z SEQUENTIALLY (all accesses are
//       intra-wave-band; LDS in-order per wave; program order
//       read-x -> write-h1 -> read-h1 -> write-z is alias-safe).
//   (c) z written once at the end, coalesced float4 (as R17).
//   LDS = 17408(xs) + 9216(h2s) + 5888(b3s) = 32.5 KB -> 4 blocks/CU;
//   regs ~112 (<=128 bucket) -> 16 waves/CU = 2x R17 occupancy.
// Spline/MFMA arithmetic bit-identical to R18 (validated).
// ---------------------------------------------------------------------------
__global__ __launch_bounds__(256, 4) void fused_kernel(
    const float* __restrict__ x,
    const unsigned short* __restrict__ B1hi,
    const unsigned short* __restrict__ B1lo,
    const float* __restrict__ b1,
    const unsigned short* __restrict__ B2hi,
    const unsigned short* __restrict__ B2lo,
    const float* __restrict__ b2,
    const unsigned short* __restrict__ B3hi,
    const unsigned short* __restrict__ B3lo,
    const float* __restrict__ b3,
    float* __restrict__ out, int B) {
  __shared__ float xs[64][68];     // x -> h1 -> z (sequential reuse)
  __shared__ float h2s[64][36];    // stride 36: 16B-aligned b128 A-frag reads
  __shared__ float b3s[64 * NM];   // all 64 d biases: [d][m]

  const int t = threadIdx.x;
  const int b0 = blockIdx.x * 64;

  // ---- stage x: 64x64, 4 float4/thread, coalesced ----
  #pragma unroll
  for (int u = 0; u < 4; ++u) {
    const int idx = t + u * 256;
    const int rr = idx >> 4, c4 = (idx & 15) * 4;
    const float4 v = *reinterpret_cast<const float4*>(
        x + (size_t)b0 * 64 + (size_t)idx * 4);
    xs[rr][c4 + 0] = v.x; xs[rr][c4 + 1] = v.y;
    xs[rr][c4 + 2] = v.z; xs[rr][c4 + 3] = v.w;
  }
  // ---- stage b3 for all d: b3s[d*NM+m] = b3[m*64 + d] ----
  for (int idx = t; idx < 64 * NM; idx += 256) {
    const int dl = idx / NM, m = idx - dl * NM;
    b3s[idx] = b3[m * 64 + dl];
  }
  __syncthreads();                 // barrier 1: staging done

  const int lane = t & 63;
  const int wv   = __builtin_amdgcn_readfirstlane(t >> 6);  // wave 0..3
  const int mt   = wv;                  // M-tile: rows mt*16..mt*16+15
  const int col  = lane & 15;
  const int quad = lane >> 4;
  const int arow = mt * 16 + col;       // A-fragment row for all 3 layers
  const int row0 = mt * 16 + quad * 4;

  // ---- hoist spline x-values to registers (xs will be overwritten) ----
  float xvv[4][4];                      // [dc][reg]
  #pragma unroll
  for (int dc = 0; dc < 4; ++dc)
    #pragma unroll
    for (int reg = 0; reg < 4; ++reg)
      xvv[dc][reg] = xs[row0 + reg][dc * 16 + col];

  // ---- layer 1 (MFMA): A-frags from xs, h1 written back into xs ----
  {
    short8 ahi[2], alo[2];
    #pragma unroll
    for (int kt = 0; kt < 2; ++kt)
      cvt_hilo(&xs[arow][kt * 32 + quad * 8], ahi[kt], alo[kt]);

    #pragma unroll
    for (int nt = 0; nt < 4; ++nt) {
      const float bv = b1[nt * 16 + col];
      f32x4 acc = {bv, bv, bv, bv};
      #pragma unroll
      for (int kt = 0; kt < 2; ++kt) {
        const size_t off = ((size_t)(nt * 2 + kt) * 64 + lane) * 8;
        const short8 bh = *reinterpret_cast<const short8*>(B1hi + off);
        const short8 bl = *reinterpret_cast<const short8*>(B1lo + off);
        acc = __builtin_amdgcn_mfma_f32_16x16x32_bf16(ahi[kt], bh, acc, 0, 0, 0);
        acc = __builtin_amdgcn_mfma_f32_16x16x32_bf16(alo[kt], bh, acc, 0, 0, 0);
        acc = __builtin_amdgcn_mfma_f32_16x16x32_bf16(ahi[kt], bl, acc, 0, 0, 0);
      }
      #pragma unroll
      for (int reg = 0; reg < 4; ++reg)
        xs[row0 + reg][nt * 16 + col] = fmaxf(acc[reg], 0.f);   // h1 in-place
    }
  }
  // no barrier: wave-band private; LDS ops in-order per wave

  // ---- layer 2 (MFMA): h1 (in xs) -> h2s ----
  {
    short8 ahi[2], alo[2];
    #pragma unroll
    for (int kt = 0; kt < 2; ++kt)
      cvt_hilo(&xs[arow][kt * 32 + quad * 8], ahi[kt], alo[kt]);

    #pragma unroll
    for (int nt = 0; nt < 2; ++nt) {
      const float bv = b2[nt * 16 + col];
      f32x4 acc = {bv, bv, bv, bv};
      #pragma unroll
      for (int kt = 0; kt < 2; ++kt) {
        const size_t off = ((size_t)(nt * 2 + kt) * 64 + lane) * 8;
        const short8 bh = *reinterpret_cast<const short8*>(B2hi + off);
        const short8 bl = *reinterpret_cast<const short8*>(B2lo + off);
        acc = __builtin_amdgcn_mfma_f32_16x16x32_bf16(ahi[kt], bh, acc, 0, 0, 0);
        acc = __builtin_amdgcn_mfma_f32_16x16x32_bf16(alo[kt], bh, acc, 0, 0, 0);
        acc = __builtin_amdgcn_mfma_f32_16x16x32_bf16(ahi[kt], bl, acc, 0, 0, 0);
      }
      #pragma unroll
      for (int reg = 0; reg < 4; ++reg)
        h2s[row0 + reg][nt * 16 + col] = fmaxf(acc[reg], 0.f);
    }
  }
  // no barrier: wave-band private

  // ---- layer 3 (grouped MFMA) + spline; z into xs ----
  short8 ahi, alo;
  cvt_hilo(&h2s[arow][quad * 8], ahi, alo);

  float ldr[4] = {0.f, 0.f, 0.f, 0.f};
  const float WSC = 1.0f - 1e-3f * 8.0f;

  #pragma unroll 1
  for (int dc = 0; dc < 4; ++dc) {
    const int d = dc * 16 + col;          // this lane's d

    float xcv[4], fidx[4], xkv[4], wkv[4], ykv[4], hkv[4];

    // ======== group W: m in [0,8) -> xc, idx, xk, wk ========
    {
      f32x4 acc[8];
      #pragma unroll
      for (int m = 0; m < 8; ++m) {
        const float bv = b3s[d * NM + m];
        acc[m] = (f32x4){bv, bv, bv, bv};
      }
      #pragma unroll
      for (int m = 0; m < 8; ++m) {
        const size_t off = ((size_t)(4 * m + dc) * 64 + lane) * 8;
        const short8 bh = *reinterpret_cast<const short8*>(B3hi + off);
        const short8 bl = *reinterpret_cast<const short8*>(B3lo + off);
        acc[m] = __builtin_amdgcn_mfma_f32_16x16x32_bf16(ahi, bh, acc[m], 0, 0, 0);
        acc[m] = __builtin_amdgcn_mfma_f32_16x16x32_bf16(alo, bh, acc[m], 0, 0, 0);
        acc[m] = __builtin_amdgcn_mfma_f32_16x16x32_bf16(ahi, bl, acc[m], 0, 0, 0);
      }
      #pragma unroll
      for (int reg = 0; reg < 4; ++reg) {
        float ew[8], sw = 0.f;
        #pragma unroll
        for (int k = 0; k < 8; ++k) { ew[k] = __expf(acc[k][reg]); sw += ew[k]; }
        const float invw = fastrcp(sw);
        float cumw[9];
        cumw[0] = -3.f;
        float cw = 0.f;
        #pragma unroll
        for (int k = 0; k < 7; ++k) {
          cw += 1e-3f + WSC * (ew[k] * invw);
          cumw[k + 1] = fmaf(6.f, cw, -3.f);
        }
        cumw[8] = 3.f;

        const float xv = xvv[dc][reg];
        const float xc = fminf(fmaxf(xv, -3.f), 3.f);
        float fi = 0.f, xk = cumw[0], xk1 = cumw[1];
        #pragma unroll
        for (int k = 1; k < 8; ++k) {
          const bool s = xc >= cumw[k] + 1e-6f;
          xk  = s ? cumw[k]     : xk;
          xk1 = s ? cumw[k + 1] : xk1;
          fi  = s ? (float)k    : fi;
        }
        xcv[reg] = xc; fidx[reg] = fi; xkv[reg] = xk; wkv[reg] = xk1 - xk;
      }
    }

    // ======== group H: m in [8,16) -> yk, hk ========
    {
      f32x4 acc[8];
      #pragma unroll
      for (int m = 0; m < 8; ++m) {
        const float bv = b3s[d * NM + (8 + m)];
        acc[m] = (f32x4){bv, bv, bv, bv};
      }
      #pragma unroll
      for (int m = 0; m < 8; ++m) {
        const size_t off = ((size_t)(4 * (8 + m) + dc) * 64 + lane) * 8;
        const short8 bh = *reinterpret_cast<const short8*>(B3hi + off);
        const short8 bl = *reinterpret_cast<const short8*>(B3lo + off);
        acc[m] = __builtin_amdgcn_mfma_f32_16x16x32_bf16(ahi, bh, acc[m], 0, 0, 0);
        acc[m] = __builtin_amdgcn_mfma_f32_16x16x32_bf16(alo, bh, acc[m], 0, 0, 0);
        acc[m] = __builtin_amdgcn_mfma_f32_16x16x32_bf16(ahi, bl, acc[m], 0, 0, 0);
      }
      #pragma unroll
      for (int reg = 0; reg < 4; ++reg) {
        float eh[8], sh = 0.f;
        #pragma unroll
        for (int k = 0; k < 8; ++k) { eh[k] = __expf(acc[k][reg]); sh += eh[k]; }
        const float invh = fastrcp(sh);
        float cumh[9];
        cumh[0] = -3.f;
        float ch = 0.f;
        #pragma unroll
        for (int k = 0; k < 7; ++k) {
          ch += 1e-3f + WSC * (eh[k] * invh);
          cumh[k + 1] = fmaf(6.f, ch, -3.f);
        }
        cumh[8] = 3.f;

        float yk = cumh[0], yk1 = cumh[1];
        #pragma unroll
        for (int k = 1; k < 8; ++k) {
          const bool s = fidx[reg] >= (float)k;
          yk  = s ? cumh[k]     : yk;
          yk1 = s ? cumh[k + 1] : yk1;
        }
        ykv[reg] = yk; hkv[reg] = yk1 - yk;
      }
    }

    // ======== group D: m in [16,23) -> dk, dk1 + final spline ========
    {
      f32x4 acc[7];
      #pragma unroll
      for (int m = 0; m < 7; ++m) {
        const float bv = b3s[d * NM + (16 + m)];
        acc[m] = (f32x4){bv, bv, bv, bv};
      }
      #pragma unroll
      for (int m = 0; m < 7; ++m) {
        const size_t off = ((size_t)(4 * (16 + m) + dc) * 64 + lane) * 8;
        const short8 bh = *reinterpret_cast<const short8*>(B3hi + off);
        const short8 bl = *reinterpret_cast<const short8*>(B3lo + off);
        acc[m] = __builtin_amdgcn_mfma_f32_16x16x32_bf16(ahi, bh, acc[m], 0, 0, 0);
        acc[m] = __builtin_amdgcn_mfma_f32_16x16x32_bf16(alo, bh, acc[m], 0, 0, 0);
        acc[m] = __builtin_amdgcn_mfma_f32_16x16x32_bf16(ahi, bl, acc[m], 0, 0, 0);
      }
      #pragma unroll
      for (int reg = 0; reg < 4; ++reg) {
        float p[7];
        #pragma unroll
        for (int k = 0; k < 7; ++k) p[k] = acc[k][reg];
        const float fi = fidx[reg];

        // dk  = idx==0 ? 1 : 1e-3+sp(p[idx-1]);  pa = p[idx-1] for idx>=1
        // dk1 = idx==7 ? 1 : 1e-3+sp(p[idx]);    pb = p[idx]   for idx<=6
        float pa = p[0], pb = p[0];
        #pragma unroll
        for (int k = 2; k < 8; ++k) pa = (fi >= (float)k) ? p[k - 1] : pa;
        #pragma unroll
        for (int k = 1; k < 7; ++k) pb = (fi >= (float)k) ? p[k] : pb;
        const float spa = 1e-3f + softplus_f(pa);
        const float spb = 1e-3f + softplus_f(pb);
        const float dk  = (fi >= 0.5f) ? spa : 1.f;
        const float dk1 = (fi >= 6.5f) ? 1.f : spb;

        const float xc = xcv[reg], xk = xkv[reg], wk = wkv[reg];
        const float yk = ykv[reg], hk = hkv[reg];
        const float invwk = fastrcp(wk);
        const float delta = hk * invwk;
        const float theta = (xc - xk) * invwk;
        const float omt = 1.f - theta;
        const float tt = theta * omt;
        const float th2 = theta * theta;
        const float num = hk * (delta * th2 + dk * tt);
        const float den = delta + (dk + dk1 - 2.f * delta) * tt;
        const float rden = fastrcp(den);
        const float yv = yk + num * rden;
        const float dnum =
            delta * delta * (dk1 * th2 + 2.f * delta * tt + dk * omt * omt);
        const float ldv = __logf(dnum * rden * rden);

        const float xv = xvv[dc][reg];
        const bool inside = (xv >= -3.f) && (xv <= 3.f);
        xs[row0 + reg][d] = inside ? yv : xv;     // z into LDS
        ldr[reg] += inside ? ldv : 0.f;
      }
    }
  }

  // ---- log-det: reduce across the 16 cols (lane bits 0..3) ----
  #pragma unroll
  for (int mask = 1; mask <= 8; mask <<= 1) {
    #pragma unroll
    for (int reg = 0; reg < 4; ++reg)
      ldr[reg] += __shfl_xor(ldr[reg], mask, 64);
  }

  if (col == 0) {
    #pragma unroll
    for (int reg = 0; reg < 4; ++reg)
      out[(size_t)B * 64 + b0 + row0 + reg] = ldr[reg];
  }

  __syncthreads();                 // barrier 2: all z writes done

  // ---- coalesced z write: full 64 columns, float4 ----
  #pragma unroll
  for (int u = 0; u < 4; ++u) {
    const int idx = t + u * 256;
    const int rr = idx >> 4, c4 = (idx & 15) * 4;
    const float4 v = make_float4(xs[rr][c4 + 0], xs[rr][c4 + 1],
                                 xs[rr][c4 + 2], xs[rr][c4 + 3]);
    *reinterpret_cast<float4*>(out + (size_t)(b0 + rr) * 64 + c4) = v;
  }
}

extern "C" void kernel_launch(void* const* d_in, const int* in_sizes, int n_in,
                              void* d_out, int out_size, void* d_ws, size_t ws_size,
                              hipStream_t stream) {
  const float* x  = (const float*)d_in[0];
  const float* W1 = (const float*)d_in[1];
  const float* b1 = (const float*)d_in[2];
  const float* W2 = (const float*)d_in[3];
  const float* b2 = (const float*)d_in[4];
  const float* W3 = (const float*)d_in[5];
  const float* b3 = (const float*)d_in[6];
  float* out = (float*)d_out;
  char* ws   = (char*)d_ws;

  unsigned short* B1hi = (unsigned short*)(ws);           // 4096 u16
  unsigned short* B1lo = (unsigned short*)(ws + 8192);    // 4096 u16
  unsigned short* B2hi = (unsigned short*)(ws + 16384);   // 2048 u16
  unsigned short* B2lo = (unsigned short*)(ws + 20480);   // 2048 u16
  unsigned short* B3hi = (unsigned short*)(ws + 24576);   // 47104 u16
  unsigned short* B3lo = (unsigned short*)(ws + 118784);  // 47104 u16

  const int B = in_sizes[0] / 64;        // 32768

  prep_kernel<<<184, 256, 0, stream>>>(W1, W2, W3, B1hi, B1lo, B2hi, B2lo,
                                       B3hi, B3lo);

  fused_kernel<<<B / 64, 256, 0, stream>>>(
      x, B1hi, B1lo, b1, B2hi, B2lo, b2, B3hi, B3lo, b3, out, B);
}

// Round 6
// 108.690 us; speedup vs baseline: 1.2111x; 1.0810x over previous
//
#include <hip/hip_runtime.h>

#define NM 23        // 3*K - 1, K = 8

typedef short short8 __attribute__((ext_vector_type(8)));
typedef float f32x4 __attribute__((ext_vector_type(4)));

__device__ __forceinline__ float softplus_f(float v) {
  return fmaxf(v, 0.f) + __logf(1.f + __expf(-fabsf(v)));
}

__device__ __forceinline__ float fastrcp(float v) {
  return __builtin_amdgcn_rcpf(v);   // v_rcp_f32, ~1-2 ulp
}

__device__ __forceinline__ unsigned short bf16_rne(float x) {
  unsigned u = __float_as_uint(x);
  u += 0x7FFFu + ((u >> 16) & 1u);
  return (unsigned short)(u >> 16);
}

// ---------------------------------------------------------------------------
// Prep (unchanged, validated). Fragment layout:
// B[k][n], n = ntile*16 + (lane&15), k = kstep*32 + (lane>>4)*8 + j,
// stored lane-contiguous 16B at ((ntile*nk + kstep)*64 + lane)*8 + j.
// ---------------------------------------------------------------------------
__global__ __launch_bounds__(256) void prep_kernel(
    const float* __restrict__ W1, const float* __restrict__ W2,
    const float* __restrict__ W3,
    unsigned short* __restrict__ B1hi, unsigned short* __restrict__ B1lo,
    unsigned short* __restrict__ B2hi, unsigned short* __restrict__ B2lo,
    unsigned short* __restrict__ B3hi, unsigned short* __restrict__ B3lo) {
  const int idx = blockIdx.x * 256 + threadIdx.x;
  const int j = idx & 7, lane = (idx >> 3) & 63;
  const int col = lane & 15, quad = lane >> 4;

  if (idx < 4096) {                     // W1 fragments: nt<4, kt<2
    const int rest = idx >> 9, kt = rest & 1, nt = rest >> 1;
    const int k = kt * 32 + quad * 8 + j;   // d
    const int n = nt * 16 + col;            // i
    const float v = ((n % 63) >= k) ? W1[n * 64 + k] : 0.f;
    const unsigned short h = bf16_rne(v);
    B1hi[idx] = h;
    B1lo[idx] = bf16_rne(v - __uint_as_float(((unsigned)h) << 16));
  }
  if (idx < 2048) {                     // W2 fragments: nt<2, kt<2
    const int rest = idx >> 9, kt = rest & 1, nt = rest >> 1;
    const int k = kt * 32 + quad * 8 + j;   // i
    const int n = nt * 16 + col;            // j
    const float v = ((k % 63) <= n) ? W2[n * 64 + k] : 0.f;
    const unsigned short h = bf16_rne(v);
    B2hi[idx] = h;
    B2lo[idx] = bf16_rne(v - __uint_as_float(((unsigned)h) << 16));
  }
  if (idx < 92 * 64 * 8) {              // W3 fragments
    const int nt = idx >> 9;
    const int n = nt * 16 + col;        // n = m*64 + d
    const int d = n & 63;
    const int k = quad * 8 + j;
    const float v = (k < d) ? W3[(size_t)n * 32 + k] : 0.f;
    const unsigned short h = bf16_rne(v);
    B3hi[idx] = h;
    B3lo[idx] = bf16_rne(v - __uint_as_float(((unsigned)h) << 16));
  }
}

// f32x4 pair (LDS, 16B-aligned) -> bf16 hi/lo fragment
__device__ __forceinline__ void cvt_hilo(const float* src, short8& hi,
                                         short8& lo) {
  const f32x4 a0 = *reinterpret_cast<const f32x4*>(src);
  const f32x4 a1 = *reinterpret_cast<const f32x4*>(src + 4);
  const float af[8] = {a0.x, a0.y, a0.z, a0.w, a1.x, a1.y, a1.z, a1.w};
  #pragma unroll
  for (int j = 0; j < 8; ++j) {
    const unsigned short h = bf16_rne(af[j]);
    hi[j] = (short)h;
    lo[j] = (short)bf16_rne(af[j] - __uint_as_float(((unsigned)h) << 16));
  }
}

// ---------------------------------------------------------------------------
// Fused kernel. R20 CHANGE (R19 post-mortem: occupancy was GRID-capped —
// 512 blocks = exactly 2/CU = 2048 waves vs 8192 machine capacity; register/
// LDS diet couldn't help. Supply more waves):
//   (a) d-half split: each 64-row tile handled by TWO blocks, each doing
//       cols [ds*32, ds*32+32). Grid 512 -> 1024 = 4 blocks/CU = 16
//       waves/CU, 2x wave supply. MLP (layers 1+2) recomputed per half —
//       now cheap (36 MFMA/wave) post-R16; the R15 merge trade flips back.
//   (b) z staged in h2s (sequential reuse h2 -> z, wave-band private),
//       written as 32-col = 128B full lines: no write amplification.
//   (c) ld via per-half partials in ldws + ld_reduce dispatch (R14 pattern).
//   (d) XCD pairing: the two halves of a row-tile are 8 apart in blockIdx
//       (ds = (bid>>3)&1) so they land on the same XCD (%8 round-robin) and
//       share the x tile + B3 stream in that XCD's L2.
// Per-point math bit-identical to R19 (validated).
// ---------------------------------------------------------------------------
__global__ __launch_bounds__(256, 4) void fused_kernel(
    const float* __restrict__ x,
    const unsigned short* __restrict__ B1hi,
    const unsigned short* __restrict__ B1lo,
    const float* __restrict__ b1,
    const unsigned short* __restrict__ B2hi,
    const unsigned short* __restrict__ B2lo,
    const float* __restrict__ b2,
    const unsigned short* __restrict__ B3hi,
    const unsigned short* __restrict__ B3lo,
    const float* __restrict__ b3,
    float* __restrict__ out, float* __restrict__ ldws, int B) {
  __shared__ float xs[64][68];     // x -> h1 (sequential reuse)
  __shared__ float h2s[64][36];    // h2 -> z (sequential reuse)
  __shared__ float b3s[32 * NM];   // this d-half's biases: [dl][m]

  const int t = threadIdx.x;
  const int bid = blockIdx.x;
  const int ds = (bid >> 3) & 1;                       // d-half
  const int rb = ((bid >> 4) << 3) | (bid & 7);        // row-block
  const int b0 = rb * 64;

  // ---- stage x: 64x64, 4 float4/thread, coalesced ----
  #pragma unroll
  for (int u = 0; u < 4; ++u) {
    const int idx = t + u * 256;
    const int rr = idx >> 4, c4 = (idx & 15) * 4;
    const float4 v = *reinterpret_cast<const float4*>(
        x + (size_t)b0 * 64 + (size_t)idx * 4);
    xs[rr][c4 + 0] = v.x; xs[rr][c4 + 1] = v.y;
    xs[rr][c4 + 2] = v.z; xs[rr][c4 + 3] = v.w;
  }
  // ---- stage b3 for this half: b3s[dl*NM+m] = b3[m*64 + ds*32 + dl] ----
  for (int idx = t; idx < 32 * NM; idx += 256) {
    const int dl = idx / NM, m = idx - dl * NM;
    b3s[idx] = b3[m * 64 + ds * 32 + dl];
  }
  __syncthreads();                 // barrier 1: staging done

  const int lane = t & 63;
  const int wv   = __builtin_amdgcn_readfirstlane(t >> 6);  // wave 0..3
  const int mt   = wv;                  // M-tile: rows mt*16..mt*16+15
  const int col  = lane & 15;
  const int quad = lane >> 4;
  const int arow = mt * 16 + col;       // A-fragment row for all 3 layers
  const int row0 = mt * 16 + quad * 4;

  // ---- hoist this half's spline x-values to registers ----
  float xvv[2][4];                      // [dcl][reg]
  #pragma unroll
  for (int dcl = 0; dcl < 2; ++dcl)
    #pragma unroll
    for (int reg = 0; reg < 4; ++reg)
      xvv[dcl][reg] = xs[row0 + reg][ds * 32 + dcl * 16 + col];

  // ---- layer 1 (MFMA): A-frags from xs, h1 written back into xs ----
  {
    short8 ahi[2], alo[2];
    #pragma unroll
    for (int kt = 0; kt < 2; ++kt)
      cvt_hilo(&xs[arow][kt * 32 + quad * 8], ahi[kt], alo[kt]);

    #pragma unroll
    for (int nt = 0; nt < 4; ++nt) {
      const float bv = b1[nt * 16 + col];
      f32x4 acc = {bv, bv, bv, bv};
      #pragma unroll
      for (int kt = 0; kt < 2; ++kt) {
        const size_t off = ((size_t)(nt * 2 + kt) * 64 + lane) * 8;
        const short8 bh = *reinterpret_cast<const short8*>(B1hi + off);
        const short8 bl = *reinterpret_cast<const short8*>(B1lo + off);
        acc = __builtin_amdgcn_mfma_f32_16x16x32_bf16(ahi[kt], bh, acc, 0, 0, 0);
        acc = __builtin_amdgcn_mfma_f32_16x16x32_bf16(alo[kt], bh, acc, 0, 0, 0);
        acc = __builtin_amdgcn_mfma_f32_16x16x32_bf16(ahi[kt], bl, acc, 0, 0, 0);
      }
      #pragma unroll
      for (int reg = 0; reg < 4; ++reg)
        xs[row0 + reg][nt * 16 + col] = fmaxf(acc[reg], 0.f);   // h1 in-place
    }
  }
  // no barrier: wave-band private; LDS ops in-order per wave

  // ---- layer 2 (MFMA): h1 (in xs) -> h2s ----
  {
    short8 ahi[2], alo[2];
    #pragma unroll
    for (int kt = 0; kt < 2; ++kt)
      cvt_hilo(&xs[arow][kt * 32 + quad * 8], ahi[kt], alo[kt]);

    #pragma unroll
    for (int nt = 0; nt < 2; ++nt) {
      const float bv = b2[nt * 16 + col];
      f32x4 acc = {bv, bv, bv, bv};
      #pragma unroll
      for (int kt = 0; kt < 2; ++kt) {
        const size_t off = ((size_t)(nt * 2 + kt) * 64 + lane) * 8;
        const short8 bh = *reinterpret_cast<const short8*>(B2hi + off);
        const short8 bl = *reinterpret_cast<const short8*>(B2lo + off);
        acc = __builtin_amdgcn_mfma_f32_16x16x32_bf16(ahi[kt], bh, acc, 0, 0, 0);
        acc = __builtin_amdgcn_mfma_f32_16x16x32_bf16(alo[kt], bh, acc, 0, 0, 0);
        acc = __builtin_amdgcn_mfma_f32_16x16x32_bf16(ahi[kt], bl, acc, 0, 0, 0);
      }
      #pragma unroll
      for (int reg = 0; reg < 4; ++reg)
        h2s[row0 + reg][nt * 16 + col] = fmaxf(acc[reg], 0.f);
    }
  }
  // no barrier: wave-band private

  // ---- layer 3 (grouped MFMA) + spline; z into h2s ----
  short8 ahi, alo;
  cvt_hilo(&h2s[arow][quad * 8], ahi, alo);

  float ldr[4] = {0.f, 0.f, 0.f, 0.f};
  const float WSC = 1.0f - 1e-3f * 8.0f;

  #pragma unroll 1
  for (int dcl = 0; dcl < 2; ++dcl) {
    const int dc = ds * 2 + dcl;          // global d-chunk 0..3
    const int dl = dcl * 16 + col;        // local col 0..31

    float xcv[4], fidx[4], xkv[4], wkv[4], ykv[4], hkv[4];

    // ======== group W: m in [0,8) -> xc, idx, xk, wk ========
    {
      f32x4 acc[8];
      #pragma unroll
      for (int m = 0; m < 8; ++m) {
        const float bv = b3s[dl * NM + m];
        acc[m] = (f32x4){bv, bv, bv, bv};
      }
      #pragma unroll
      for (int m = 0; m < 8; ++m) {
        const size_t off = ((size_t)(4 * m + dc) * 64 + lane) * 8;
        const short8 bh = *reinterpret_cast<const short8*>(B3hi + off);
        const short8 bl = *reinterpret_cast<const short8*>(B3lo + off);
        acc[m] = __builtin_amdgcn_mfma_f32_16x16x32_bf16(ahi, bh, acc[m], 0, 0, 0);
        acc[m] = __builtin_amdgcn_mfma_f32_16x16x32_bf16(alo, bh, acc[m], 0, 0, 0);
        acc[m] = __builtin_amdgcn_mfma_f32_16x16x32_bf16(ahi, bl, acc[m], 0, 0, 0);
      }
      #pragma unroll
      for (int reg = 0; reg < 4; ++reg) {
        float ew[8], sw = 0.f;
        #pragma unroll
        for (int k = 0; k < 8; ++k) { ew[k] = __expf(acc[k][reg]); sw += ew[k]; }
        const float invw = fastrcp(sw);
        float cumw[9];
        cumw[0] = -3.f;
        float cw = 0.f;
        #pragma unroll
        for (int k = 0; k < 7; ++k) {
          cw += 1e-3f + WSC * (ew[k] * invw);
          cumw[k + 1] = fmaf(6.f, cw, -3.f);
        }
        cumw[8] = 3.f;

        const float xv = xvv[dcl][reg];
        const float xc = fminf(fmaxf(xv, -3.f), 3.f);
        float fi = 0.f, xk = cumw[0], xk1 = cumw[1];
        #pragma unroll
        for (int k = 1; k < 8; ++k) {
          const bool s = xc >= cumw[k] + 1e-6f;
          xk  = s ? cumw[k]     : xk;
          xk1 = s ? cumw[k + 1] : xk1;
          fi  = s ? (float)k    : fi;
        }
        xcv[reg] = xc; fidx[reg] = fi; xkv[reg] = xk; wkv[reg] = xk1 - xk;
      }
    }

    // ======== group H: m in [8,16) -> yk, hk ========
    {
      f32x4 acc[8];
      #pragma unroll
      for (int m = 0; m < 8; ++m) {
        const float bv = b3s[dl * NM + (8 + m)];
        acc[m] = (f32x4){bv, bv, bv, bv};
      }
      #pragma unroll
      for (int m = 0; m < 8; ++m) {
        const size_t off = ((size_t)(4 * (8 + m) + dc) * 64 + lane) * 8;
        const short8 bh = *reinterpret_cast<const short8*>(B3hi + off);
        const short8 bl = *reinterpret_cast<const short8*>(B3lo + off);
        acc[m] = __builtin_amdgcn_mfma_f32_16x16x32_bf16(ahi, bh, acc[m], 0, 0, 0);
        acc[m] = __builtin_amdgcn_mfma_f32_16x16x32_bf16(alo, bh, acc[m], 0, 0, 0);
        acc[m] = __builtin_amdgcn_mfma_f32_16x16x32_bf16(ahi, bl, acc[m], 0, 0, 0);
      }
      #pragma unroll
      for (int reg = 0; reg < 4; ++reg) {
        float eh[8], sh = 0.f;
        #pragma unroll
        for (int k = 0; k < 8; ++k) { eh[k] = __expf(acc[k][reg]); sh += eh[k]; }
        const float invh = fastrcp(sh);
        float cumh[9];
        cumh[0] = -3.f;
        float ch = 0.f;
        #pragma unroll
        for (int k = 0; k < 7; ++k) {
          ch += 1e-3f + WSC * (eh[k] * invh);
          cumh[k + 1] = fmaf(6.f, ch, -3.f);
        }
        cumh[8] = 3.f;

        float yk = cumh[0], yk1 = cumh[1];
        #pragma unroll
        for (int k = 1; k < 8; ++k) {
          const bool s = fidx[reg] >= (float)k;
          yk  = s ? cumh[k]     : yk;
          yk1 = s ? cumh[k + 1] : yk1;
        }
        ykv[reg] = yk; hkv[reg] = yk1 - yk;
      }
    }

    // ======== group D: m in [16,23) -> dk, dk1 + final spline ========
    {
      f32x4 acc[7];
      #pragma unroll
      for (int m = 0; m < 7; ++m) {
        const float bv = b3s[dl * NM + (16 + m)];
        acc[m] = (f32x4){bv, bv, bv, bv};
      }
      #pragma unroll
      for (int m = 0; m < 7; ++m) {
        const size_t off = ((size_t)(4 * (16 + m) + dc) * 64 + lane) * 8;
        const short8 bh = *reinterpret_cast<const short8*>(B3hi + off);
        const short8 bl = *reinterpret_cast<const short8*>(B3lo + off);
        acc[m] = __builtin_amdgcn_mfma_f32_16x16x32_bf16(ahi, bh, acc[m], 0, 0, 0);
        acc[m] = __builtin_amdgcn_mfma_f32_16x16x32_bf16(alo, bh, acc[m], 0, 0, 0);
        acc[m] = __builtin_amdgcn_mfma_f32_16x16x32_bf16(ahi, bl, acc[m], 0, 0, 0);
      }
      #pragma unroll
      for (int reg = 0; reg < 4; ++reg) {
        float p[7];
        #pragma unroll
        for (int k = 0; k < 7; ++k) p[k] = acc[k][reg];
        const float fi = fidx[reg];

        // dk  = idx==0 ? 1 : 1e-3+sp(p[idx-1]);  pa = p[idx-1] for idx>=1
        // dk1 = idx==7 ? 1 : 1e-3+sp(p[idx]);    pb = p[idx]   for idx<=6
        float pa = p[0], pb = p[0];
        #pragma unroll
        for (int k = 2; k < 8; ++k) pa = (fi >= (float)k) ? p[k - 1] : pa;
        #pragma unroll
        for (int k = 1; k < 7; ++k) pb = (fi >= (float)k) ? p[k] : pb;
        const float spa = 1e-3f + softplus_f(pa);
        const float spb = 1e-3f + softplus_f(pb);
        const float dk  = (fi >= 0.5f) ? spa : 1.f;
        const float dk1 = (fi >= 6.5f) ? 1.f : spb;

        const float xc = xcv[reg], xk = xkv[reg], wk = wkv[reg];
        const float yk = ykv[reg], hk = hkv[reg];
        const float invwk = fastrcp(wk);
        const float delta = hk * invwk;
        const float theta = (xc - xk) * invwk;
        const float omt = 1.f - theta;
        const float tt = theta * omt;
        const float th2 = theta * theta;
        const float num = hk * (delta * th2 + dk * tt);
        const float den = delta + (dk + dk1 - 2.f * delta) * tt;
        const float rden = fastrcp(den);
        const float yv = yk + num * rden;
        const float dnum =
            delta * delta * (dk1 * th2 + 2.f * delta * tt + dk * omt * omt);
        const float ldv = __logf(dnum * rden * rden);

        const float xv = xvv[dcl][reg];
        const bool inside = (xv >= -3.f) && (xv <= 3.f);
        h2s[row0 + reg][dl] = inside ? yv : xv;   // z into LDS (h2s reuse)
        ldr[reg] += inside ? ldv : 0.f;
      }
    }
  }

  // ---- log-det (this half): reduce across the 16 cols ----
  #pragma unroll
  for (int mask = 1; mask <= 8; mask <<= 1) {
    #pragma unroll
    for (int reg = 0; reg < 4; ++reg)
      ldr[reg] += __shfl_xor(ldr[reg], mask, 64);
  }

  if (col == 0) {
    #pragma unroll
    for (int reg = 0; reg < 4; ++reg)
      ldws[(size_t)ds * B + b0 + row0 + reg] = ldr[reg];
  }

  __syncthreads();                 // barrier 2: all z writes done

  // ---- coalesced z write: this half's 32 columns, float4 (128B/row) ----
  #pragma unroll
  for (int u = 0; u < 2; ++u) {
    const int idx = t + u * 256;
    const int rr = idx >> 3, c4 = (idx & 7) * 4;
    const float4 v = make_float4(h2s[rr][c4 + 0], h2s[rr][c4 + 1],
                                 h2s[rr][c4 + 2], h2s[rr][c4 + 3]);
    *reinterpret_cast<float4*>(
        out + (size_t)(b0 + rr) * 64 + ds * 32 + c4) = v;
  }
}

// ---------------------------------------------------------------------------
// Sum the 2 d-half log-det partials.
// ---------------------------------------------------------------------------
__global__ __launch_bounds__(256) void ld_reduce(
    const float* __restrict__ ldws, float* __restrict__ out, int B) {
  const int idx = blockIdx.x * 256 + threadIdx.x;
  if (idx < B) out[(size_t)B * 64 + idx] = ldws[idx] + ldws[B + idx];
}

extern "C" void kernel_launch(void* const* d_in, const int* in_sizes, int n_in,
                              void* d_out, int out_size, void* d_ws, size_t ws_size,
                              hipStream_t stream) {
  const float* x  = (const float*)d_in[0];
  const float* W1 = (const float*)d_in[1];
  const float* b1 = (const float*)d_in[2];
  const float* W2 = (const float*)d_in[3];
  const float* b2 = (const float*)d_in[4];
  const float* W3 = (const float*)d_in[5];
  const float* b3 = (const float*)d_in[6];
  float* out = (float*)d_out;
  char* ws   = (char*)d_ws;

  unsigned short* B1hi = (unsigned short*)(ws);           // 4096 u16
  unsigned short* B1lo = (unsigned short*)(ws + 8192);    // 4096 u16
  unsigned short* B2hi = (unsigned short*)(ws + 16384);   // 2048 u16
  unsigned short* B2lo = (unsigned short*)(ws + 20480);   // 2048 u16
  unsigned short* B3hi = (unsigned short*)(ws + 24576);   // 47104 u16
  unsigned short* B3lo = (unsigned short*)(ws + 118784);  // 47104 u16
  float* ldws = (float*)(ws + 212992);                    // 2*B floats

  const int B = in_sizes[0] / 64;        // 32768

  prep_kernel<<<184, 256, 0, stream>>>(W1, W2, W3, B1hi, B1lo, B2hi, B2lo,
                                       B3hi, B3lo);

  fused_kernel<<<(B / 64) * 2, 256, 0, stream>>>(
      x, B1hi, B1lo, b1, B2hi, B2lo, b2, B3hi, B3lo, b3, out, ldws, B);

  ld_reduce<<<(B + 255) / 256, 256, 0, stream>>>(ldws, out, B);
}

// Round 7
// 106.315 us; speedup vs baseline: 1.2381x; 1.0223x over previous
//
#include <hip/hip_runtime.h>

#define NM 23        // 3*K - 1, K = 8

typedef short short8 __attribute__((ext_vector_type(8)));
typedef float f32x4 __attribute__((ext_vector_type(4)));

#define LOG2E 1.44269504088896340736f

__device__ __forceinline__ float softplus_f(float v) {
  return fmaxf(v, 0.f) + __logf(1.f + __expf(-fabsf(v)));
}

__device__ __forceinline__ float fastrcp(float v) {
  return __builtin_amdgcn_rcpf(v);   // v_rcp_f32, ~1-2 ulp
}

__device__ __forceinline__ unsigned short bf16_rne(float x) {
  unsigned u = __float_as_uint(x);
  u += 0x7FFFu + ((u >> 16) & 1u);
  return (unsigned short)(u >> 16);
}

// ---------------------------------------------------------------------------
// Prep. R21: W3 rows for m<16 (W and H softmax logits) pre-scaled by log2(e)
// so the fused kernel can use bare v_exp_f32 (exp2f) with no per-point mul:
// exp2(p*log2e) == exp(p) exactly (softmax invariant to the rounding).
// Fragment layout unchanged (validated):
// B[k][n], n = ntile*16 + (lane&15), k = kstep*32 + (lane>>4)*8 + j,
// stored lane-contiguous 16B at ((ntile*nk + kstep)*64 + lane)*8 + j.
// ---------------------------------------------------------------------------
__global__ __launch_bounds__(256) void prep_kernel(
    const float* __restrict__ W1, const float* __restrict__ W2,
    const float* __restrict__ W3,
    unsigned short* __restrict__ B1hi, unsigned short* __restrict__ B1lo,
    unsigned short* __restrict__ B2hi, unsigned short* __restrict__ B2lo,
    unsigned short* __restrict__ B3hi, unsigned short* __restrict__ B3lo) {
  const int idx = blockIdx.x * 256 + threadIdx.x;
  const int j = idx & 7, lane = (idx >> 3) & 63;
  const int col = lane & 15, quad = lane >> 4;

  if (idx < 4096) {                     // W1 fragments: nt<4, kt<2
    const int rest = idx >> 9, kt = rest & 1, nt = rest >> 1;
    const int k = kt * 32 + quad * 8 + j;   // d
    const int n = nt * 16 + col;            // i
    const float v = ((n % 63) >= k) ? W1[n * 64 + k] : 0.f;
    const unsigned short h = bf16_rne(v);
    B1hi[idx] = h;
    B1lo[idx] = bf16_rne(v - __uint_as_float(((unsigned)h) << 16));
  }
  if (idx < 2048) {                     // W2 fragments: nt<2, kt<2
    const int rest = idx >> 9, kt = rest & 1, nt = rest >> 1;
    const int k = kt * 32 + quad * 8 + j;   // i
    const int n = nt * 16 + col;            // j
    const float v = ((k % 63) <= n) ? W2[n * 64 + k] : 0.f;
    const unsigned short h = bf16_rne(v);
    B2hi[idx] = h;
    B2lo[idx] = bf16_rne(v - __uint_as_float(((unsigned)h) << 16));
  }
  if (idx < 92 * 64 * 8) {              // W3 fragments
    const int nt = idx >> 9;
    const int n = nt * 16 + col;        // n = m*64 + d
    const int d = n & 63;
    const int m = n >> 6;
    const int k = quad * 8 + j;
    float v = (k < d) ? W3[(size_t)n * 32 + k] : 0.f;
    if (m < 16) v *= LOG2E;             // exp2 domain for softmax logits
    const unsigned short h = bf16_rne(v);
    B3hi[idx] = h;
    B3lo[idx] = bf16_rne(v - __uint_as_float(((unsigned)h) << 16));
  }
}

// f32x4 pair (LDS or global, 16B-aligned) -> bf16 hi/lo fragment
__device__ __forceinline__ void cvt_hilo(const float* src, short8& hi,
                                         short8& lo) {
  const f32x4 a0 = *reinterpret_cast<const f32x4*>(src);
  const f32x4 a1 = *reinterpret_cast<const f32x4*>(src + 4);
  const float af[8] = {a0.x, a0.y, a0.z, a0.w, a1.x, a1.y, a1.z, a1.w};
  #pragma unroll
  for (int j = 0; j < 8; ++j) {
    const unsigned short h = bf16_rne(af[j]);
    hi[j] = (short)h;
    lo[j] = (short)bf16_rne(af[j] - __uint_as_float(((unsigned)h) << 16));
  }
}

// ---------------------------------------------------------------------------
// Fused kernel. R21 CHANGE (supply the full machine without MLP duplication):
// 32-row x 64-col blocks, 512 threads (8 waves), grid = B/32 = 1024 blocks
// = 8192 waves = machine capacity.
//   - L1: 8 tiles (mt<2, nt<4) -> one per wave. ZERO duplication (R20 ran
//     the whole MLP twice per row-tile).
//   - L2: 4 tiles (mt<2, nt<2) -> waves 0..3; others wait (short phase).
//   - L3+spline: (mt<2, dc<4) -> one per wave, 4 points/lane.
//   - log-det completed in-block via ldp[4][32] -> ld_reduce dispatch GONE.
//   - x read direct from global (tile L2-hot; R18 showed read-side cost is
//     ~2 us; its 6x WRITE blowup is avoided: z still staged in LDS and
//     written as full 128B lines).
//   - W/H softmax in exp2 domain (prep pre-scale): exp2f = bare v_exp_f32,
//     -16 v_mul per point.
// Per-point spline math otherwise bit-identical to R20 (validated).
// LDS: h1s 8.7K + h2s(z) 8.7K + b3s 5.9K + ldp 0.5K = 23.8 KB.
// ---------------------------------------------------------------------------
__global__ __launch_bounds__(512, 4) void fused_kernel(
    const float* __restrict__ x,
    const unsigned short* __restrict__ B1hi,
    const unsigned short* __restrict__ B1lo,
    const float* __restrict__ b1,
    const unsigned short* __restrict__ B2hi,
    const unsigned short* __restrict__ B2lo,
    const float* __restrict__ b2,
    const unsigned short* __restrict__ B3hi,
    const unsigned short* __restrict__ B3lo,
    const float* __restrict__ b3,
    float* __restrict__ out, int B) {
  __shared__ float h1s[32][68];    // stride 68: 16B-aligned b128 A-frag reads
  __shared__ float h2s[32][68];    // h2 (cols 0..31) -> z (cols 0..63)
  __shared__ float b3s[64 * NM];   // biases [d][m], W/H pre-scaled by log2e
  __shared__ float ldp[4][32];     // per-dc log-det partials

  const int t = threadIdx.x;
  const int b0 = blockIdx.x * 32;

  // ---- stage b3: b3s[d*NM+m] = b3[m*64+d] (*log2e for m<16) ----
  for (int idx = t; idx < 64 * NM; idx += 512) {
    const int dl = idx / NM, m = idx - dl * NM;
    const float s = (m < 16) ? LOG2E : 1.f;
    b3s[idx] = b3[m * 64 + dl] * s;
  }
  __syncthreads();                 // B1: b3 staged

  const int lane = t & 63;
  const int wv   = __builtin_amdgcn_readfirstlane(t >> 6);  // wave 0..7
  const int col  = lane & 15;
  const int quad = lane >> 4;

  // ---- layer 1 (MFMA): tile (mt1, nt1) per wave, A-frags from global x ----
  {
    const int mt1 = wv >> 2, nt1 = wv & 3;
    const float* xrow = x + (size_t)(b0 + mt1 * 16 + col) * 64;
    short8 ahi[2], alo[2];
    #pragma unroll
    for (int kt = 0; kt < 2; ++kt)
      cvt_hilo(xrow + kt * 32 + quad * 8, ahi[kt], alo[kt]);

    const float bv = b1[nt1 * 16 + col];
    f32x4 acc = {bv, bv, bv, bv};
    #pragma unroll
    for (int kt = 0; kt < 2; ++kt) {
      const size_t off = ((size_t)(nt1 * 2 + kt) * 64 + lane) * 8;
      const short8 bh = *reinterpret_cast<const short8*>(B1hi + off);
      const short8 bl = *reinterpret_cast<const short8*>(B1lo + off);
      acc = __builtin_amdgcn_mfma_f32_16x16x32_bf16(ahi[kt], bh, acc, 0, 0, 0);
      acc = __builtin_amdgcn_mfma_f32_16x16x32_bf16(alo[kt], bh, acc, 0, 0, 0);
      acc = __builtin_amdgcn_mfma_f32_16x16x32_bf16(ahi[kt], bl, acc, 0, 0, 0);
    }
    #pragma unroll
    for (int reg = 0; reg < 4; ++reg)
      h1s[mt1 * 16 + quad * 4 + reg][nt1 * 16 + col] = fmaxf(acc[reg], 0.f);
  }
  __syncthreads();                 // B2: h1 complete

  // ---- layer 2 (MFMA): tile (mt2, nt2), waves 0..3 ----
  if (wv < 4) {
    const int mt2 = wv >> 1, nt2 = wv & 1;
    short8 ahi[2], alo[2];
    #pragma unroll
    for (int kt = 0; kt < 2; ++kt)
      cvt_hilo(&h1s[mt2 * 16 + col][kt * 32 + quad * 8], ahi[kt], alo[kt]);

    const float bv = b2[nt2 * 16 + col];
    f32x4 acc = {bv, bv, bv, bv};
    #pragma unroll
    for (int kt = 0; kt < 2; ++kt) {
      const size_t off = ((size_t)(nt2 * 2 + kt) * 64 + lane) * 8;
      const short8 bh = *reinterpret_cast<const short8*>(B2hi + off);
      const short8 bl = *reinterpret_cast<const short8*>(B2lo + off);
      acc = __builtin_amdgcn_mfma_f32_16x16x32_bf16(ahi[kt], bh, acc, 0, 0, 0);
      acc = __builtin_amdgcn_mfma_f32_16x16x32_bf16(alo[kt], bh, acc, 0, 0, 0);
      acc = __builtin_amdgcn_mfma_f32_16x16x32_bf16(ahi[kt], bl, acc, 0, 0, 0);
    }
    #pragma unroll
    for (int reg = 0; reg < 4; ++reg)
      h2s[mt2 * 16 + quad * 4 + reg][nt2 * 16 + col] = fmaxf(acc[reg], 0.f);
  }
  __syncthreads();                 // B3: h2 complete

  // ---- layer 3 setup: wave = (mt, dc); hoist A-frag + x before z writes ----
  const int mt = wv >> 2, dc = wv & 3;
  const int row0 = mt * 16 + quad * 4;
  const int d = dc * 16 + col;

  short8 ahi, alo;
  cvt_hilo(&h2s[mt * 16 + col][quad * 8], ahi, alo);

  float xvv[4];
  #pragma unroll
  for (int reg = 0; reg < 4; ++reg)
    xvv[reg] = x[(size_t)(b0 + row0 + reg) * 64 + d];

  __syncthreads();                 // B4: A-frags hoisted; h2s free for z

  float ldr[4] = {0.f, 0.f, 0.f, 0.f};
  const float WSC = 1.0f - 1e-3f * 8.0f;

  float xcv[4], fidx[4], xkv[4], wkv[4], ykv[4], hkv[4];

  // ======== group W: m in [0,8) -> xc, idx, xk, wk ========
  {
    f32x4 acc[8];
    #pragma unroll
    for (int m = 0; m < 8; ++m) {
      const float bv = b3s[d * NM + m];
      acc[m] = (f32x4){bv, bv, bv, bv};
    }
    #pragma unroll
    for (int m = 0; m < 8; ++m) {
      const size_t off = ((size_t)(4 * m + dc) * 64 + lane) * 8;
      const short8 bh = *reinterpret_cast<const short8*>(B3hi + off);
      const short8 bl = *reinterpret_cast<const short8*>(B3lo + off);
      acc[m] = __builtin_amdgcn_mfma_f32_16x16x32_bf16(ahi, bh, acc[m], 0, 0, 0);
      acc[m] = __builtin_amdgcn_mfma_f32_16x16x32_bf16(alo, bh, acc[m], 0, 0, 0);
      acc[m] = __builtin_amdgcn_mfma_f32_16x16x32_bf16(ahi, bl, acc[m], 0, 0, 0);
    }
    #pragma unroll
    for (int reg = 0; reg < 4; ++reg) {
      float ew[8], sw = 0.f;
      #pragma unroll
      for (int k = 0; k < 8; ++k) { ew[k] = exp2f(acc[k][reg]); sw += ew[k]; }
      const float invw = fastrcp(sw);
      float cumw[9];
      cumw[0] = -3.f;
      float cw = 0.f;
      #pragma unroll
      for (int k = 0; k < 7; ++k) {
        cw += 1e-3f + WSC * (ew[k] * invw);
        cumw[k + 1] = fmaf(6.f, cw, -3.f);
      }
      cumw[8] = 3.f;

      const float xv = xvv[reg];
      const float xc = fminf(fmaxf(xv, -3.f), 3.f);
      float fi = 0.f, xk = cumw[0], xk1 = cumw[1];
      #pragma unroll
      for (int k = 1; k < 8; ++k) {
        const bool s = xc >= cumw[k] + 1e-6f;
        xk  = s ? cumw[k]     : xk;
        xk1 = s ? cumw[k + 1] : xk1;
        fi  = s ? (float)k    : fi;
      }
      xcv[reg] = xc; fidx[reg] = fi; xkv[reg] = xk; wkv[reg] = xk1 - xk;
    }
  }

  // ======== group H: m in [8,16) -> yk, hk ========
  {
    f32x4 acc[8];
    #pragma unroll
    for (int m = 0; m < 8; ++m) {
      const float bv = b3s[d * NM + (8 + m)];
      acc[m] = (f32x4){bv, bv, bv, bv};
    }
    #pragma unroll
    for (int m = 0; m < 8; ++m) {
      const size_t off = ((size_t)(4 * (8 + m) + dc) * 64 + lane) * 8;
      const short8 bh = *reinterpret_cast<const short8*>(B3hi + off);
      const short8 bl = *reinterpret_cast<const short8*>(B3lo + off);
      acc[m] = __builtin_amdgcn_mfma_f32_16x16x32_bf16(ahi, bh, acc[m], 0, 0, 0);
      acc[m] = __builtin_amdgcn_mfma_f32_16x16x32_bf16(alo, bh, acc[m], 0, 0, 0);
      acc[m] = __builtin_amdgcn_mfma_f32_16x16x32_bf16(ahi, bl, acc[m], 0, 0, 0);
    }
    #pragma unroll
    for (int reg = 0; reg < 4; ++reg) {
      float eh[8], sh = 0.f;
      #pragma unroll
      for (int k = 0; k < 8; ++k) { eh[k] = exp2f(acc[k][reg]); sh += eh[k]; }
      const float invh = fastrcp(sh);
      float cumh[9];
      cumh[0] = -3.f;
      float ch = 0.f;
      #pragma unroll
      for (int k = 0; k < 7; ++k) {
        ch += 1e-3f + WSC * (eh[k] * invh);
        cumh[k + 1] = fmaf(6.f, ch, -3.f);
      }
      cumh[8] = 3.f;

      float yk = cumh[0], yk1 = cumh[1];
      #pragma unroll
      for (int k = 1; k < 8; ++k) {
        const bool s = fidx[reg] >= (float)k;
        yk  = s ? cumh[k]     : yk;
        yk1 = s ? cumh[k + 1] : yk1;
      }
      ykv[reg] = yk; hkv[reg] = yk1 - yk;
    }
  }

  // ======== group D: m in [16,23) -> dk, dk1 + final spline ========
  {
    f32x4 acc[7];
    #pragma unroll
    for (int m = 0; m < 7; ++m) {
      const float bv = b3s[d * NM + (16 + m)];
      acc[m] = (f32x4){bv, bv, bv, bv};
    }
    #pragma unroll
    for (int m = 0; m < 7; ++m) {
      const size_t off = ((size_t)(4 * (16 + m) + dc) * 64 + lane) * 8;
      const short8 bh = *reinterpret_cast<const short8*>(B3hi + off);
      const short8 bl = *reinterpret_cast<const short8*>(B3lo + off);
      acc[m] = __builtin_amdgcn_mfma_f32_16x16x32_bf16(ahi, bh, acc[m], 0, 0, 0);
      acc[m] = __builtin_amdgcn_mfma_f32_16x16x32_bf16(alo, bh, acc[m], 0, 0, 0);
      acc[m] = __builtin_amdgcn_mfma_f32_16x16x32_bf16(ahi, bl, acc[m], 0, 0, 0);
    }
    #pragma unroll
    for (int reg = 0; reg < 4; ++reg) {
      float p[7];
      #pragma unroll
      for (int k = 0; k < 7; ++k) p[k] = acc[k][reg];
      const float fi = fidx[reg];

      // dk  = idx==0 ? 1 : 1e-3+sp(p[idx-1]);  dk1 = idx==7 ? 1 : 1e-3+sp(p[idx])
      float pa = p[0], pb = p[0];
      #pragma unroll
      for (int k = 2; k < 8; ++k) pa = (fi >= (float)k) ? p[k - 1] : pa;
      #pragma unroll
      for (int k = 1; k < 7; ++k) pb = (fi >= (float)k) ? p[k] : pb;
      const float spa = 1e-3f + softplus_f(pa);
      const float spb = 1e-3f + softplus_f(pb);
      const float dk  = (fi >= 0.5f) ? spa : 1.f;
      const float dk1 = (fi >= 6.5f) ? 1.f : spb;

      const float xc = xcv[reg], xk = xkv[reg], wk = wkv[reg];
      const float yk = ykv[reg], hk = hkv[reg];
      const float invwk = fastrcp(wk);
      const float delta = hk * invwk;
      const float theta = (xc - xk) * invwk;
      const float omt = 1.f - theta;
      const float tt = theta * omt;
      const float th2 = theta * theta;
      const float num = hk * (delta * th2 + dk * tt);
      const float den = delta + (dk + dk1 - 2.f * delta) * tt;
      const float rden = fastrcp(den);
      const float yv = yk + num * rden;
      const float dnum =
          delta * delta * (dk1 * th2 + 2.f * delta * tt + dk * omt * omt);
      const float ldv = __logf(dnum * rden * rden);

      const float xv = xvv[reg];
      const bool inside = (xv >= -3.f) && (xv <= 3.f);
      h2s[row0 + reg][d] = inside ? yv : xv;    // z into LDS (h2s reuse)
      ldr[reg] += inside ? ldv : 0.f;
    }
  }

  // ---- log-det: reduce this wave's 16 cols (lane bits 0..3) ----
  #pragma unroll
  for (int mask = 1; mask <= 8; mask <<= 1) {
    #pragma unroll
    for (int reg = 0; reg < 4; ++reg)
      ldr[reg] += __shfl_xor(ldr[reg], mask, 64);
  }
  if (col == 0) {
    #pragma unroll
    for (int reg = 0; reg < 4; ++reg)
      ldp[dc][row0 + reg] = ldr[reg];
  }

  __syncthreads();                 // B5: z + ld partials done

  // ---- ld: complete 64-d sum per row ----
  if (t < 32)
    out[(size_t)B * 64 + b0 + t] =
        (ldp[0][t] + ldp[1][t]) + (ldp[2][t] + ldp[3][t]);

  // ---- coalesced z write: 32 rows x 64 cols, 1 float4/thread ----
  {
    const int rr = t >> 4, c4 = (t & 15) * 4;
    const float4 v = make_float4(h2s[rr][c4 + 0], h2s[rr][c4 + 1],
                                 h2s[rr][c4 + 2], h2s[rr][c4 + 3]);
    *reinterpret_cast<float4*>(out + (size_t)(b0 + rr) * 64 + c4) = v;
  }
}

extern "C" void kernel_launch(void* const* d_in, const int* in_sizes, int n_in,
                              void* d_out, int out_size, void* d_ws, size_t ws_size,
                              hipStream_t stream) {
  const float* x  = (const float*)d_in[0];
  const float* W1 = (const float*)d_in[1];
  const float* b1 = (const float*)d_in[2];
  const float* W2 = (const float*)d_in[3];
  const float* b2 = (const float*)d_in[4];
  const float* W3 = (const float*)d_in[5];
  const float* b3 = (const float*)d_in[6];
  float* out = (float*)d_out;
  char* ws   = (char*)d_ws;

  unsigned short* B1hi = (unsigned short*)(ws);           // 4096 u16
  unsigned short* B1lo = (unsigned short*)(ws + 8192);    // 4096 u16
  unsigned short* B2hi = (unsigned short*)(ws + 16384);   // 2048 u16
  unsigned short* B2lo = (unsigned short*)(ws + 20480);   // 2048 u16
  unsigned short* B3hi = (unsigned short*)(ws + 24576);   // 47104 u16
  unsigned short* B3lo = (unsigned short*)(ws + 118784);  // 47104 u16

  const int B = in_sizes[0] / 64;        // 32768

  prep_kernel<<<184, 256, 0, stream>>>(W1, W2, W3, B1hi, B1lo, B2hi, B2lo,
                                       B3hi, B3lo);

  fused_kernel<<<B / 32, 512, 0, stream>>>(
      x, B1hi, B1lo, b1, B2hi, B2lo, b2, B3hi, B3lo, b3, out, B);
}